// Round 1
// baseline (5668.587 us; speedup 1.0000x reference)
//
#include <hip/hip_runtime.h>

// Problem constants
constexpr int cB = 4, cS = 2048, cD = 1024, cH = 16, cE = 8, cF = 4096;
constexpr int cN = cB * cS;          // 8192 tokens
constexpr int cDH = 64;
constexpr int cCAP = 1280;           // int(1.25 * 8192 / 8)
constexpr int cECAP = cE * cCAP;     // 10240

// ---------------------------------------------------------------------------
// LayerNorm: one block per token, 256 threads, float4 per thread.
// ---------------------------------------------------------------------------
__global__ __launch_bounds__(256) void ln_kernel(const float* __restrict__ x,
                                                 const float* __restrict__ g,
                                                 const float* __restrict__ bb,
                                                 float* __restrict__ y) {
  __shared__ float red[8];
  const int row = blockIdx.x;
  const int t = threadIdx.x;
  const float4 v = ((const float4*)(x + (size_t)row * cD))[t];
  float s = v.x + v.y + v.z + v.w;
#pragma unroll
  for (int m = 32; m >= 1; m >>= 1) s += __shfl_xor(s, m, 64);
  if ((t & 63) == 0) red[t >> 6] = s;
  __syncthreads();
  const float mean = (red[0] + red[1] + red[2] + red[3]) * (1.0f / cD);
  const float dx = v.x - mean, dy = v.y - mean, dz = v.z - mean, dw = v.w - mean;
  float ss = dx * dx + dy * dy + dz * dz + dw * dw;
#pragma unroll
  for (int m = 32; m >= 1; m >>= 1) ss += __shfl_xor(ss, m, 64);
  if ((t & 63) == 0) red[4 + (t >> 6)] = ss;
  __syncthreads();
  const float var = (red[4] + red[5] + red[6] + red[7]) * (1.0f / cD);
  const float inv = rsqrtf(var + 1e-5f);
  const float4 gg = ((const float4*)g)[t];
  const float4 b4 = ((const float4*)bb)[t];
  float4 o;
  o.x = dx * inv * gg.x + b4.x;
  o.y = dy * inv * gg.y + b4.y;
  o.z = dz * inv * gg.z + b4.z;
  o.w = dw * inv * gg.w + b4.w;
  ((float4*)(y + (size_t)row * cD))[t] = o;
}

// ---------------------------------------------------------------------------
// fp32 tiled GEMM. C[M,N] = A[M,K] * B + bias (+relu) (+residual R).
// BLAYOUT 0: B is [N,K] row-major (i.e. C = A * B^T)  -> qkv / out_proj
// BLAYOUT 1: B is [K,N] row-major                      -> expert FFN
// Tile 128x128x16, 256 threads, 8x8 microtile split as 2x2 blocks of 4x4
// (columns {tx*4..+3} and {64+tx*4..+3}) so LDS reads stay 2-way (free).
// blockIdx.z = batch (expert); strides sA/sB/sBias/sC advance per batch.
// All of M,N divisible by 128 and K by 16 for our shapes.
// ---------------------------------------------------------------------------
template <int BLAYOUT, bool RELU, bool RESID>
__global__ __launch_bounds__(256) void gemm128(
    const float* __restrict__ A, size_t sA,
    const float* __restrict__ Bp, size_t sB,
    const float* __restrict__ bias, size_t sBias,
    const float* __restrict__ R,
    float* __restrict__ C, size_t sC,
    int M, int N, int K, int lda, int ldb, int ldc) {
  __shared__ float As[16][132];
  __shared__ float Bs[16][132];
  const int z = blockIdx.z;
  A += (size_t)z * sA;
  Bp += (size_t)z * sB;
  bias += (size_t)z * sBias;
  C += (size_t)z * sC;
  const float* Rz = RESID ? (R + (size_t)z * sC) : nullptr;
  const int n0 = blockIdx.x * 128;
  const int m0 = blockIdx.y * 128;
  const int tid = threadIdx.x;
  const int tx = tid & 15, ty = tid >> 4;
  float acc[8][8];
#pragma unroll
  for (int i = 0; i < 8; i++)
#pragma unroll
    for (int j = 0; j < 8; j++) acc[i][j] = 0.f;

  for (int k0 = 0; k0 < K; k0 += 16) {
    __syncthreads();
#pragma unroll
    for (int u = 0; u < 2; u++) {
      const int a = tid + u * 256;
      const int m = a >> 2, kq = (a & 3) << 2;
      const float4 v = *(const float4*)(A + (size_t)(m0 + m) * lda + k0 + kq);
      As[kq + 0][m] = v.x;
      As[kq + 1][m] = v.y;
      As[kq + 2][m] = v.z;
      As[kq + 3][m] = v.w;
    }
    if (BLAYOUT == 0) {
#pragma unroll
      for (int u = 0; u < 2; u++) {
        const int a = tid + u * 256;
        const int n = a >> 2, kq = (a & 3) << 2;
        const float4 v = *(const float4*)(Bp + (size_t)(n0 + n) * ldb + k0 + kq);
        Bs[kq + 0][n] = v.x;
        Bs[kq + 1][n] = v.y;
        Bs[kq + 2][n] = v.z;
        Bs[kq + 3][n] = v.w;
      }
    } else {
#pragma unroll
      for (int u = 0; u < 2; u++) {
        const int a = tid + u * 256;
        const int kk = a >> 5, n4 = (a & 31) << 2;
        const float4 v = *(const float4*)(Bp + (size_t)(k0 + kk) * ldb + n0 + n4);
        *(float4*)&Bs[kk][n4] = v;
      }
    }
    __syncthreads();
#pragma unroll
    for (int kk = 0; kk < 16; kk++) {
      const float4 a0 = *(const float4*)&As[kk][ty * 4];
      const float4 a1 = *(const float4*)&As[kk][64 + ty * 4];
      const float4 b0 = *(const float4*)&Bs[kk][tx * 4];
      const float4 b1 = *(const float4*)&Bs[kk][64 + tx * 4];
      const float ar[8] = {a0.x, a0.y, a0.z, a0.w, a1.x, a1.y, a1.z, a1.w};
      const float br[8] = {b0.x, b0.y, b0.z, b0.w, b1.x, b1.y, b1.z, b1.w};
#pragma unroll
      for (int i = 0; i < 8; i++)
#pragma unroll
        for (int j = 0; j < 8; j++) acc[i][j] += ar[i] * br[j];
    }
  }
#pragma unroll
  for (int i = 0; i < 8; i++) {
    const int m = m0 + ((i < 4) ? (ty * 4 + i) : (64 + ty * 4 + i - 4));
#pragma unroll
    for (int cg = 0; cg < 2; cg++) {
      const int c0 = n0 + cg * 64 + tx * 4;
      const float4 bv = *(const float4*)(bias + c0);
      float4 r;
      r.x = acc[i][cg * 4 + 0] + bv.x;
      r.y = acc[i][cg * 4 + 1] + bv.y;
      r.z = acc[i][cg * 4 + 2] + bv.z;
      r.w = acc[i][cg * 4 + 3] + bv.w;
      if (RELU) {
        r.x = fmaxf(r.x, 0.f);
        r.y = fmaxf(r.y, 0.f);
        r.z = fmaxf(r.z, 0.f);
        r.w = fmaxf(r.w, 0.f);
      }
      if (RESID) {
        const float4 rv = *(const float4*)(Rz + (size_t)m * ldc + c0);
        r.x += rv.x;
        r.y += rv.y;
        r.z += rv.z;
        r.w += rv.w;
      }
      *(float4*)(C + (size_t)m * ldc + c0) = r;
    }
  }
}

// ---------------------------------------------------------------------------
// Flash-style attention, fp32. Grid (S/64, H, B), block 256 = 4 waves.
// Each wave owns 16 queries; lane <-> k-index within the 64-wide K tile.
// Online softmax state (m, l) replicated per lane via wave butterflies.
// qkv layout: [token][3*D] with q at +0, k at +1024, v at +2048, head h at h*64.
// ---------------------------------------------------------------------------
__global__ __launch_bounds__(256) void attn_kernel(const float* __restrict__ qkv,
                                                   const unsigned char* __restrict__ pad,
                                                   float* __restrict__ out) {
  __shared__ float Qs[64][68];  // pad 68: aligned float4 broadcast reads
  __shared__ float Ks[64][65];  // pad 65: lane-varying b32 reads, 2-way free
  __shared__ float Vs[64][65];
  __shared__ float Ps[64][68];
  __shared__ float Mk[64];
  const int q0 = blockIdx.x << 6;
  const int h = blockIdx.y;
  const int b = blockIdx.z;
  const int tid = threadIdx.x;
  const int wid = tid >> 6, lane = tid & 63;

  for (int a = tid; a < 1024; a += 256) {
    const int r = a >> 4, c4 = (a & 15) << 2;
    const float4 v =
        *(const float4*)(qkv + (size_t)(b * cS + q0 + r) * (3 * cD) + h * cDH + c4);
    *(float4*)&Qs[r][c4] = v;
  }

  float mprev[16], lrun[16], O[16];
#pragma unroll
  for (int q = 0; q < 16; q++) {
    mprev[q] = -1e30f;
    lrun[q] = 0.f;
    O[q] = 0.f;
  }

  for (int kt = 0; kt < cS / 64; kt++) {
    const int k0 = kt << 6;
    __syncthreads();  // previous tile's reads done before reload
    for (int a = tid; a < 1024; a += 256) {
      const int r = a >> 4, c4 = (a & 15) << 2;
      const size_t base = (size_t)(b * cS + k0 + r) * (3 * cD) + h * cDH + c4;
      const float4 kv = *(const float4*)(qkv + base + cD);
      const float4 vv = *(const float4*)(qkv + base + 2 * cD);
      Ks[r][c4 + 0] = kv.x;
      Ks[r][c4 + 1] = kv.y;
      Ks[r][c4 + 2] = kv.z;
      Ks[r][c4 + 3] = kv.w;
      Vs[r][c4 + 0] = vv.x;
      Vs[r][c4 + 1] = vv.y;
      Vs[r][c4 + 2] = vv.z;
      Vs[r][c4 + 3] = vv.w;
    }
    if (tid < 64) Mk[tid] = pad[b * cS + k0 + tid] ? 1.0f : 0.0f;
    __syncthreads();

    float s[16];
#pragma unroll
    for (int q = 0; q < 16; q++) s[q] = 0.f;
#pragma unroll 4
    for (int dc = 0; dc < 16; dc++) {
      const float k0r = Ks[lane][dc * 4 + 0];
      const float k1r = Ks[lane][dc * 4 + 1];
      const float k2r = Ks[lane][dc * 4 + 2];
      const float k3r = Ks[lane][dc * 4 + 3];
#pragma unroll
      for (int q = 0; q < 16; q++) {
        const float4 qv = *(const float4*)&Qs[wid * 16 + q][dc * 4];
        s[q] += qv.x * k0r + qv.y * k1r + qv.z * k2r + qv.w * k3r;
      }
    }
    const bool masked = (Mk[lane] != 0.0f);
#pragma unroll
    for (int q = 0; q < 16; q++) {
      const float sf = masked ? -1e9f : s[q] * 0.125f;  // 1/sqrt(64)
      float tmax = sf;
#pragma unroll
      for (int m = 32; m >= 1; m >>= 1) tmax = fmaxf(tmax, __shfl_xor(tmax, m, 64));
      const float mnew = fmaxf(mprev[q], tmax);
      const float p = __expf(sf - mnew);
      float ts = p;
#pragma unroll
      for (int m = 32; m >= 1; m >>= 1) ts += __shfl_xor(ts, m, 64);
      const float alpha = __expf(mprev[q] - mnew);
      lrun[q] = lrun[q] * alpha + ts;
      O[q] *= alpha;
      mprev[q] = mnew;
      Ps[wid * 16 + q][lane] = p;  // only this wave reads back rows [16w,16w+16)
    }
#pragma unroll 4
    for (int kc = 0; kc < 16; kc++) {
      const float v0 = Vs[kc * 4 + 0][lane];
      const float v1 = Vs[kc * 4 + 1][lane];
      const float v2 = Vs[kc * 4 + 2][lane];
      const float v3 = Vs[kc * 4 + 3][lane];
#pragma unroll
      for (int q = 0; q < 16; q++) {
        const float4 pv = *(const float4*)&Ps[wid * 16 + q][kc * 4];
        O[q] += pv.x * v0 + pv.y * v1 + pv.z * v2 + pv.w * v3;
      }
    }
  }
#pragma unroll
  for (int q = 0; q < 16; q++) {
    const int tok = b * cS + q0 + wid * 16 + q;
    out[(size_t)tok * cD + h * cDH + lane] = O[q] / lrun[q];
  }
}

// ---------------------------------------------------------------------------
// Router: one wave per token. lane -> (expert e = lane&7, d-slice lane>>3).
// Coalesced router_w reads (idx = lane + 64*i). Exact fp32 logits; softmax,
// first-index argmax, gate; accumulates P-sums and z-loss via LDS + atomics.
// ---------------------------------------------------------------------------
__global__ __launch_bounds__(256) void router_kernel(
    const float* __restrict__ x2, const float* __restrict__ rw,
    const float* __restrict__ rb, const unsigned char* __restrict__ pad,
    float* __restrict__ gate, int* __restrict__ eidx, float* __restrict__ Psum,
    float* __restrict__ zsum) {
  __shared__ float Pacc[8];
  __shared__ float Zacc;
  if (threadIdx.x < 8) Pacc[threadIdx.x] = 0.f;
  if (threadIdx.x == 8) Zacc = 0.f;
  __syncthreads();
  const int tid = threadIdx.x, wid = tid >> 6, lane = tid & 63;
  const int e = lane & 7, dbase = lane >> 3;
  for (int tok = blockIdx.x * 4 + wid; tok < cN; tok += gridDim.x * 4) {
    const float* xr = x2 + (size_t)tok * cD;
    float partial = 0.f;
#pragma unroll 8
    for (int i = 0; i < cD / 8; i++) {
      const int d = dbase + i * 8;
      partial += xr[d] * rw[d * 8 + e];
    }
    partial += __shfl_xor(partial, 8, 64);
    partial += __shfl_xor(partial, 16, 64);
    partial += __shfl_xor(partial, 32, 64);
    const float logit = partial + rb[e];
    float mx = logit;
    mx = fmaxf(mx, __shfl_xor(mx, 1, 64));
    mx = fmaxf(mx, __shfl_xor(mx, 2, 64));
    mx = fmaxf(mx, __shfl_xor(mx, 4, 64));
    const float ex = __expf(logit - mx);
    float sm = ex;
    sm += __shfl_xor(sm, 1, 64);
    sm += __shfl_xor(sm, 2, 64);
    sm += __shfl_xor(sm, 4, 64);
    const float prob = ex / sm;
    float bv = logit;
    int bi = e;
#pragma unroll
    for (int m = 1; m < 8; m <<= 1) {
      const float ov = __shfl_xor(bv, m, 64);
      const int oi = __shfl_xor(bi, m, 64);
      if (ov > bv || (ov == bv && oi < bi)) {
        bv = ov;
        bi = oi;
      }
    }
    const float g = __shfl(prob, (lane & 0x38) | bi, 64);
    const bool valid = (pad[tok] == 0);
    if (lane == 0) {
      eidx[tok] = bi;
      gate[tok] = g;
    }
    if (valid) {
      if (lane < 8) atomicAdd(&Pacc[lane], prob);
      if (lane == 0) {
        const float lse = mx + logf(sm);
        atomicAdd(&Zacc, lse * lse);
      }
    }
  }
  __syncthreads();
  if (threadIdx.x < 8) atomicAdd(&Psum[threadIdx.x], Pacc[threadIdx.x]);
  if (threadIdx.x == 8) atomicAdd(zsum, Zacc);
}

// ---------------------------------------------------------------------------
// Capacity scan: single block. Exclusive per-expert prefix over 256 chunks of
// 32 tokens; emits flat slot (-1 if dropped/masked) and per-expert totals.
// ---------------------------------------------------------------------------
__global__ __launch_bounds__(256) void scan_kernel(const int* __restrict__ eidx,
                                                   const unsigned char* __restrict__ pad,
                                                   int* __restrict__ slot,
                                                   int* __restrict__ counts) {
  __shared__ int cnt[256][8];
  const int t = threadIdx.x;
  int lc[8] = {0, 0, 0, 0, 0, 0, 0, 0};
  const int base = t * 32;
  for (int i = 0; i < 32; i++) {
    const int tok = base + i;
    if (!pad[tok]) lc[eidx[tok]]++;
  }
#pragma unroll
  for (int e2 = 0; e2 < 8; e2++) cnt[t][e2] = lc[e2];
  __syncthreads();
  if (t < 8) {
    int run = 0;
    for (int i = 0; i < 256; i++) {
      const int v = cnt[i][t];
      cnt[i][t] = run;
      run += v;
    }
    counts[t] = run;
  }
  __syncthreads();
  int off[8];
#pragma unroll
  for (int e2 = 0; e2 < 8; e2++) off[e2] = cnt[t][e2];
  for (int i = 0; i < 32; i++) {
    const int tok = base + i;
    if (!pad[tok]) {
      const int e2 = eidx[tok];
      const int p = off[e2]++;
      slot[tok] = (p < cCAP) ? (e2 * cCAP + p) : -1;
    } else {
      slot[tok] = -1;
    }
  }
}

__global__ __launch_bounds__(256) void dispatch_kernel(const float* __restrict__ x2,
                                                       const int* __restrict__ slot,
                                                       float* __restrict__ disp) {
  const int tok = blockIdx.x;
  const int s = slot[tok];
  if (s < 0) return;
  const float4 v = ((const float4*)(x2 + (size_t)tok * cD))[threadIdx.x];
  ((float4*)(disp + (size_t)s * cD))[threadIdx.x] = v;
}

__global__ __launch_bounds__(256) void gather_kernel(const float* __restrict__ src1,
                                                     const float* __restrict__ o,
                                                     const int* __restrict__ slot,
                                                     const float* __restrict__ gate,
                                                     float* __restrict__ out) {
  const int tok = blockIdx.x;
  float4 r = ((const float4*)(src1 + (size_t)tok * cD))[threadIdx.x];
  const int s = slot[tok];
  if (s >= 0) {
    const float g = gate[tok];
    const float4 ov = ((const float4*)(o + (size_t)s * cD))[threadIdx.x];
    r.x += g * ov.x;
    r.y += g * ov.y;
    r.z += g * ov.z;
    r.w += g * ov.w;
  }
  ((float4*)(out + (size_t)tok * cD))[threadIdx.x] = r;
}

__global__ void loss_kernel(const int* __restrict__ counts,
                            const float* __restrict__ Psum,
                            const float* __restrict__ zsum,
                            float* __restrict__ out) {
  if (threadIdx.x == 0) {
    int tot = 0;
    for (int e2 = 0; e2 < 8; e2++) tot += counts[e2];
    const float denom = fmaxf((float)tot, 1.0f);
    float lp = 0.f;
    for (int e2 = 0; e2 < 8; e2++)
      lp += ((float)counts[e2] / denom) * (Psum[e2] / denom);
    out[0] = 8.0f * lp;
    out[1] = zsum[0] / denom;
  }
}

// ---------------------------------------------------------------------------
// Workspace layout (floats). o aliases the dead qkv buffer.
// ---------------------------------------------------------------------------
constexpr size_t OFF_QKV = 0;                            // N*3D = 25165824 (o reuses)
constexpr size_t OFF_X = 25165824;                       // LN1 out, then attn_out
constexpr size_t OFF_SRC1 = 33554432;
constexpr size_t OFF_X2 = 41943040;
constexpr size_t OFF_DISP = 50331648;                    // ECAP*D = 10485760
constexpr size_t OFF_H = 60817408;                       // ECAP*F = 41943040
constexpr size_t OFF_GATE = 102760448;                   // N
constexpr size_t OFF_EIDX = 102768640;                   // N ints
constexpr size_t OFF_SLOT = 102776832;                   // N ints
constexpr size_t OFF_ACC = 102785024;                    // Psum[8], zsum; counts[8]

extern "C" void kernel_launch(void* const* d_in, const int* in_sizes, int n_in,
                              void* d_out, int out_size, void* d_ws, size_t ws_size,
                              hipStream_t stream) {
  (void)in_sizes; (void)n_in; (void)out_size; (void)ws_size;
  const float* src = (const float*)d_in[0];
  const unsigned char* pad = (const unsigned char*)d_in[1];
  const float* ln1_g = (const float*)d_in[2];
  const float* ln1_b = (const float*)d_in[3];
  const float* in_proj_w = (const float*)d_in[4];
  const float* in_proj_b = (const float*)d_in[5];
  const float* out_proj_w = (const float*)d_in[6];
  const float* out_proj_b = (const float*)d_in[7];
  const float* ln2_g = (const float*)d_in[8];
  const float* ln2_b = (const float*)d_in[9];
  const float* router_w = (const float*)d_in[10];
  const float* router_b = (const float*)d_in[11];
  const float* w1 = (const float*)d_in[12];
  const float* b1 = (const float*)d_in[13];
  const float* w2 = (const float*)d_in[14];
  const float* b2 = (const float*)d_in[15];
  float* out = (float*)d_out;
  float* w = (float*)d_ws;

  float* qkv = w + OFF_QKV;
  float* xbuf = w + OFF_X;      // LN1 out, reused as attention output
  float* src1 = w + OFF_SRC1;
  float* x2 = w + OFF_X2;
  float* disp = w + OFF_DISP;
  float* hbuf = w + OFF_H;
  float* obuf = w + OFF_QKV;    // alias: qkv dead after attention
  float* gate = w + OFF_GATE;
  int* eidx = (int*)(w + OFF_EIDX);
  int* slot = (int*)(w + OFF_SLOT);
  float* Psum = w + OFF_ACC;
  float* zsum = w + OFF_ACC + 8;
  int* counts = (int*)(w + OFF_ACC + 16);

  hipMemsetAsync(Psum, 0, 9 * sizeof(float), stream);

  // 1) LN1
  ln_kernel<<<cN, 256, 0, stream>>>(src, ln1_g, ln1_b, xbuf);
  // 2) QKV projection: [8192,1024] x [3072,1024]^T
  gemm128<0, false, false><<<dim3(24, 64, 1), 256, 0, stream>>>(
      xbuf, 0, in_proj_w, 0, in_proj_b, 0, nullptr, qkv, 0,
      cN, 3 * cD, cD, cD, cD, 3 * cD);
  // 3) attention (writes over xbuf)
  attn_kernel<<<dim3(cS / 64, cH, cB), 256, 0, stream>>>(qkv, pad, xbuf);
  // 4) out_proj + residual(src) -> src1
  gemm128<0, false, true><<<dim3(8, 64, 1), 256, 0, stream>>>(
      xbuf, 0, out_proj_w, 0, out_proj_b, 0, src, src1, 0,
      cN, cD, cD, cD, cD, cD);
  // 5) LN2
  ln_kernel<<<cN, 256, 0, stream>>>(src1, ln2_g, ln2_b, x2);
  // 6) router
  router_kernel<<<256, 256, 0, stream>>>(x2, router_w, router_b, pad, gate, eidx,
                                         Psum, zsum);
  // 7) capacity scan
  scan_kernel<<<1, 256, 0, stream>>>(eidx, pad, slot, counts);
  // 8) dispatch scatter (unfilled rows stay poisoned; never gathered)
  dispatch_kernel<<<cN, 256, 0, stream>>>(x2, slot, disp);
  // 9) expert FFN layer 1: relu(d @ w1 + b1), batched over experts
  gemm128<1, true, false><<<dim3(32, 10, 8), 256, 0, stream>>>(
      disp, (size_t)cCAP * cD, w1, (size_t)cD * cF, b1, (size_t)cF, nullptr,
      hbuf, (size_t)cCAP * cF, cCAP, cF, cD, cD, cF, cF);
  // 10) expert FFN layer 2: h @ w2 + b2
  gemm128<1, false, false><<<dim3(8, 10, 8), 256, 0, stream>>>(
      hbuf, (size_t)cCAP * cF, w2, (size_t)cF * cD, b2, (size_t)cD, nullptr,
      obuf, (size_t)cCAP * cD, cCAP, cD, cF, cF, cD, cD);
  // 11) gather + residual -> out
  gather_kernel<<<cN, 256, 0, stream>>>(src1, obuf, slot, gate, out);
  // 12) losses
  loss_kernel<<<1, 64, 0, stream>>>(counts, Psum, zsum, out + (size_t)cN * cD);
}

// Round 2
// 3634.708 us; speedup vs baseline: 1.5596x; 1.5596x over previous
//
#include <hip/hip_runtime.h>

// Problem constants
constexpr int cB = 4, cS = 2048, cD = 1024, cH = 16, cE = 8, cF = 4096;
constexpr int cN = cB * cS;          // 8192 tokens
constexpr int cDH = 64;
constexpr int cCAP = 1280;           // int(1.25 * 8192 / 8)
constexpr int cECAP = cE * cCAP;     // 10240

typedef __attribute__((ext_vector_type(8))) short bf16x8;
typedef __attribute__((ext_vector_type(4))) float f32x4;
typedef __attribute__((ext_vector_type(4))) unsigned short u16x4;

__device__ inline unsigned short bf16_rne(float x) {
  unsigned u = __float_as_uint(x);
  u += 0x7FFF + ((u >> 16) & 1);
  return (unsigned short)(u >> 16);
}
__device__ inline float bf16_f(unsigned short h) {
  return __uint_as_float(((unsigned)h) << 16);
}

// ---------------------------------------------------------------------------
// LayerNorm: one block per token, 256 threads, float4 per thread.
// ---------------------------------------------------------------------------
__global__ __launch_bounds__(256) void ln_kernel(const float* __restrict__ x,
                                                 const float* __restrict__ g,
                                                 const float* __restrict__ bb,
                                                 float* __restrict__ y) {
  __shared__ float red[8];
  const int row = blockIdx.x;
  const int t = threadIdx.x;
  const float4 v = ((const float4*)(x + (size_t)row * cD))[t];
  float s = v.x + v.y + v.z + v.w;
#pragma unroll
  for (int m = 32; m >= 1; m >>= 1) s += __shfl_xor(s, m, 64);
  if ((t & 63) == 0) red[t >> 6] = s;
  __syncthreads();
  const float mean = (red[0] + red[1] + red[2] + red[3]) * (1.0f / cD);
  const float dx = v.x - mean, dy = v.y - mean, dz = v.z - mean, dw = v.w - mean;
  float ss = dx * dx + dy * dy + dz * dz + dw * dw;
#pragma unroll
  for (int m = 32; m >= 1; m >>= 1) ss += __shfl_xor(ss, m, 64);
  if ((t & 63) == 0) red[4 + (t >> 6)] = ss;
  __syncthreads();
  const float var = (red[4] + red[5] + red[6] + red[7]) * (1.0f / cD);
  const float inv = rsqrtf(var + 1e-5f);
  const float4 gg = ((const float4*)g)[t];
  const float4 b4 = ((const float4*)bb)[t];
  float4 o;
  o.x = dx * inv * gg.x + b4.x;
  o.y = dy * inv * gg.y + b4.y;
  o.z = dz * inv * gg.z + b4.z;
  o.w = dw * inv * gg.w + b4.w;
  ((float4*)(y + (size_t)row * cD))[t] = o;
}

// ---------------------------------------------------------------------------
// fp32 tiled GEMM (unchanged from round 0). C = A*B(+T) + bias (+relu)(+resid)
// ---------------------------------------------------------------------------
template <int BLAYOUT, bool RELU, bool RESID>
__global__ __launch_bounds__(256) void gemm128(
    const float* __restrict__ A, size_t sA,
    const float* __restrict__ Bp, size_t sB,
    const float* __restrict__ bias, size_t sBias,
    const float* __restrict__ R,
    float* __restrict__ C, size_t sC,
    int M, int N, int K, int lda, int ldb, int ldc) {
  __shared__ float As[16][132];
  __shared__ float Bs[16][132];
  const int z = blockIdx.z;
  A += (size_t)z * sA;
  Bp += (size_t)z * sB;
  bias += (size_t)z * sBias;
  C += (size_t)z * sC;
  const float* Rz = RESID ? (R + (size_t)z * sC) : nullptr;
  const int n0 = blockIdx.x * 128;
  const int m0 = blockIdx.y * 128;
  const int tid = threadIdx.x;
  const int tx = tid & 15, ty = tid >> 4;
  float acc[8][8];
#pragma unroll
  for (int i = 0; i < 8; i++)
#pragma unroll
    for (int j = 0; j < 8; j++) acc[i][j] = 0.f;

  for (int k0 = 0; k0 < K; k0 += 16) {
    __syncthreads();
#pragma unroll
    for (int u = 0; u < 2; u++) {
      const int a = tid + u * 256;
      const int m = a >> 2, kq = (a & 3) << 2;
      const float4 v = *(const float4*)(A + (size_t)(m0 + m) * lda + k0 + kq);
      As[kq + 0][m] = v.x;
      As[kq + 1][m] = v.y;
      As[kq + 2][m] = v.z;
      As[kq + 3][m] = v.w;
    }
    if (BLAYOUT == 0) {
#pragma unroll
      for (int u = 0; u < 2; u++) {
        const int a = tid + u * 256;
        const int n = a >> 2, kq = (a & 3) << 2;
        const float4 v = *(const float4*)(Bp + (size_t)(n0 + n) * ldb + k0 + kq);
        Bs[kq + 0][n] = v.x;
        Bs[kq + 1][n] = v.y;
        Bs[kq + 2][n] = v.z;
        Bs[kq + 3][n] = v.w;
      }
    } else {
#pragma unroll
      for (int u = 0; u < 2; u++) {
        const int a = tid + u * 256;
        const int kk = a >> 5, n4 = (a & 31) << 2;
        const float4 v = *(const float4*)(Bp + (size_t)(k0 + kk) * ldb + n0 + n4);
        *(float4*)&Bs[kk][n4] = v;
      }
    }
    __syncthreads();
#pragma unroll
    for (int kk = 0; kk < 16; kk++) {
      const float4 a0 = *(const float4*)&As[kk][ty * 4];
      const float4 a1 = *(const float4*)&As[kk][64 + ty * 4];
      const float4 b0 = *(const float4*)&Bs[kk][tx * 4];
      const float4 b1 = *(const float4*)&Bs[kk][64 + tx * 4];
      const float ar[8] = {a0.x, a0.y, a0.z, a0.w, a1.x, a1.y, a1.z, a1.w};
      const float br[8] = {b0.x, b0.y, b0.z, b0.w, b1.x, b1.y, b1.z, b1.w};
#pragma unroll
      for (int i = 0; i < 8; i++)
#pragma unroll
        for (int j = 0; j < 8; j++) acc[i][j] += ar[i] * br[j];
    }
  }
#pragma unroll
  for (int i = 0; i < 8; i++) {
    const int m = m0 + ((i < 4) ? (ty * 4 + i) : (64 + ty * 4 + i - 4));
#pragma unroll
    for (int cg = 0; cg < 2; cg++) {
      const int c0 = n0 + cg * 64 + tx * 4;
      const float4 bv = *(const float4*)(bias + c0);
      float4 r;
      r.x = acc[i][cg * 4 + 0] + bv.x;
      r.y = acc[i][cg * 4 + 1] + bv.y;
      r.z = acc[i][cg * 4 + 2] + bv.z;
      r.w = acc[i][cg * 4 + 3] + bv.w;
      if (RELU) {
        r.x = fmaxf(r.x, 0.f);
        r.y = fmaxf(r.y, 0.f);
        r.z = fmaxf(r.z, 0.f);
        r.w = fmaxf(r.w, 0.f);
      }
      if (RESID) {
        const float4 rv = *(const float4*)(Rz + (size_t)m * ldc + c0);
        r.x += rv.x;
        r.y += rv.y;
        r.z += rv.z;
        r.w += rv.w;
      }
      *(float4*)(C + (size_t)m * ldc + c0) = r;
    }
  }
}

// ---------------------------------------------------------------------------
// Pre-pass: split fp32 qkv into bf16 hi/lo arrays for MFMA attention.
// Q,K -> [b,h,s,64]; V -> transposed [b,h,64,s] (via LDS, stride 66).
// Grid (S/64, H, B), 256 threads.
// ---------------------------------------------------------------------------
__global__ __launch_bounds__(256) void qkv_split_kernel(
    const float* __restrict__ qkv,
    unsigned short* __restrict__ Qh, unsigned short* __restrict__ Ql,
    unsigned short* __restrict__ Kh, unsigned short* __restrict__ Kl,
    unsigned short* __restrict__ Vth, unsigned short* __restrict__ Vtl) {
  __shared__ float Vs[64 * 66];
  const int s0 = blockIdx.x << 6;
  const int h = blockIdx.y, b = blockIdx.z;
  const int tid = threadIdx.x;
  const size_t qkbase = ((size_t)(b * cH + h) * cS + s0) * cDH;
  const size_t vtbase = (size_t)(b * cH + h) * cDH * cS + s0;
#pragma unroll
  for (int u = 0; u < 4; u++) {
    const int a = tid + u * 256;          // 0..1023
    const int r = a >> 4, c4 = (a & 15) << 2;
    const float* rowp = qkv + (size_t)(b * cS + s0 + r) * (3 * cD) + h * cDH + c4;
    const float4 qv = *(const float4*)(rowp);
    const float4 kv = *(const float4*)(rowp + cD);
    const float4 vv = *(const float4*)(rowp + 2 * cD);
    u16x4 hq, lq, hk, lk;
    const float qa[4] = {qv.x, qv.y, qv.z, qv.w};
    const float ka[4] = {kv.x, kv.y, kv.z, kv.w};
    const float va[4] = {vv.x, vv.y, vv.z, vv.w};
#pragma unroll
    for (int i = 0; i < 4; i++) {
      const unsigned short h16 = bf16_rne(qa[i]);
      hq[i] = h16;
      lq[i] = bf16_rne(qa[i] - bf16_f(h16));
      const unsigned short h17 = bf16_rne(ka[i]);
      hk[i] = h17;
      lk[i] = bf16_rne(ka[i] - bf16_f(h17));
      Vs[(c4 + i) * 66 + r] = va[i];      // transposed fp32 stage
    }
    *(u16x4*)(Qh + qkbase + (size_t)r * cDH + c4) = hq;
    *(u16x4*)(Ql + qkbase + (size_t)r * cDH + c4) = lq;
    *(u16x4*)(Kh + qkbase + (size_t)r * cDH + c4) = hk;
    *(u16x4*)(Kl + qkbase + (size_t)r * cDH + c4) = lk;
  }
  __syncthreads();
#pragma unroll
  for (int u = 0; u < 4; u++) {
    const int a = tid + u * 256;          // 0..1023
    const int dh = a >> 4, k4 = (a & 15) << 2;
    u16x4 hv, lv;
#pragma unroll
    for (int i = 0; i < 4; i++) {
      const float x = Vs[dh * 66 + k4 + i];
      const unsigned short h16 = bf16_rne(x);
      hv[i] = h16;
      lv[i] = bf16_rne(x - bf16_f(h16));
    }
    *(u16x4*)(Vth + vtbase + (size_t)dh * cS + k4) = hv;
    *(u16x4*)(Vtl + vtbase + (size_t)dh * cS + k4) = lv;
  }
}

// ---------------------------------------------------------------------------
// Flash attention with split-bf16 MFMA (3-term products ~ fp32 fidelity).
// mfma_f32_16x16x32_bf16 layouts (verified m89/m120):
//   A: m=lane&15, k=quad*8+j ; B: n=lane&15, k=quad*8+j ; C/D: col=lane&15,
//   row=quad*4+reg.
// Block = 4 waves, 64 q rows (16/wave); loop over 64-key tiles. Softmax in
// exp2 domain. P round-trips LDS as split bf16. LDS rows padded to 72 u16
// so all b128 reads/writes are <=2-way (free).
// ---------------------------------------------------------------------------
__global__ __launch_bounds__(256) void attn_mfma_kernel(
    const unsigned short* __restrict__ Qh, const unsigned short* __restrict__ Ql,
    const unsigned short* __restrict__ Kh, const unsigned short* __restrict__ Kl,
    const unsigned short* __restrict__ Vth, const unsigned short* __restrict__ Vtl,
    const unsigned char* __restrict__ pad, float* __restrict__ out) {
  __shared__ unsigned short KsH[64 * 72];
  __shared__ unsigned short KsL[64 * 72];
  __shared__ unsigned short VsH[64 * 72];
  __shared__ unsigned short VsL[64 * 72];
  __shared__ unsigned short PsH[4 * 16 * 72];
  __shared__ unsigned short PsL[4 * 16 * 72];
  __shared__ float Mk[64];

  const int q0 = blockIdx.x << 6;
  const int h = blockIdx.y, b = blockIdx.z;
  const int tid = threadIdx.x;
  const int wid = tid >> 6, lane = tid & 63;
  const int ln = lane & 15, quad = lane >> 4;
  constexpr float SC2 = 0.125f * 1.4426950408889634f;  // scale * log2(e)

  const size_t bh = (size_t)(b * cH + h);
  const unsigned short* gKh = Kh + bh * cS * cDH;
  const unsigned short* gKl = Kl + bh * cS * cDH;
  const unsigned short* gVh = Vth + bh * cDH * cS;
  const unsigned short* gVl = Vtl + bh * cDH * cS;

  // Q fragments for this wave's 16 rows (held all kernel)
  const size_t qbase = (bh * cS + q0 + wid * 16 + ln) * cDH;
  bf16x8 qh[2], ql[2];
#pragma unroll
  for (int ks = 0; ks < 2; ks++) {
    qh[ks] = *(const bf16x8*)(Qh + qbase + ks * 32 + quad * 8);
    ql[ks] = *(const bf16x8*)(Ql + qbase + ks * 32 + quad * 8);
  }

  f32x4 Oc[4];
  float mprev[4], lrun[4];
#pragma unroll
  for (int dt = 0; dt < 4; dt++) Oc[dt] = (f32x4){0.f, 0.f, 0.f, 0.f};
#pragma unroll
  for (int r = 0; r < 4; r++) {
    mprev[r] = -1e30f;
    lrun[r] = 0.f;
  }

  for (int kt = 0; kt < cS / 64; kt++) {
    const int k0 = kt << 6;
    __syncthreads();
#pragma unroll
    for (int u = 0; u < 2; u++) {
      const int a = tid + (u << 8);       // 0..511
      const int row = a >> 3, c8 = (a & 7) << 3;
      const int ld = row * 72 + c8;
      *(uint4*)&KsH[ld] = *(const uint4*)(gKh + (size_t)(k0 + row) * cDH + c8);
      *(uint4*)&KsL[ld] = *(const uint4*)(gKl + (size_t)(k0 + row) * cDH + c8);
      *(uint4*)&VsH[ld] = *(const uint4*)(gVh + (size_t)row * cS + k0 + c8);
      *(uint4*)&VsL[ld] = *(const uint4*)(gVl + (size_t)row * cS + k0 + c8);
    }
    if (tid < 64) Mk[tid] = pad[b * cS + k0 + tid] ? -1e30f : 0.0f;
    __syncthreads();

    // ---- S = Q K^T (split 3-term) ----
    f32x4 sac[4];
#pragma unroll
    for (int st = 0; st < 4; st++) {
      f32x4 acc = (f32x4){0.f, 0.f, 0.f, 0.f};
      const unsigned short* krH = &KsH[(st * 16 + ln) * 72];
      const unsigned short* krL = &KsL[(st * 16 + ln) * 72];
#pragma unroll
      for (int ks = 0; ks < 2; ks++) {
        const bf16x8 kh = *(const bf16x8*)(krH + ks * 32 + quad * 8);
        const bf16x8 kl = *(const bf16x8*)(krL + ks * 32 + quad * 8);
        acc = __builtin_amdgcn_mfma_f32_16x16x32_bf16(qh[ks], kh, acc, 0, 0, 0);
        acc = __builtin_amdgcn_mfma_f32_16x16x32_bf16(ql[ks], kh, acc, 0, 0, 0);
        acc = __builtin_amdgcn_mfma_f32_16x16x32_bf16(qh[ks], kl, acc, 0, 0, 0);
      }
      sac[st] = acc;
    }
    float sf[4][4];
#pragma unroll
    for (int st = 0; st < 4; st++) {
      const float ma = Mk[st * 16 + ln];
#pragma unroll
      for (int r = 0; r < 4; r++) sf[st][r] = sac[st][r] * SC2 + ma;
    }
    // ---- online softmax (exp2 domain), write split P ----
#pragma unroll
    for (int r = 0; r < 4; r++) {
      float vm = fmaxf(fmaxf(sf[0][r], sf[1][r]), fmaxf(sf[2][r], sf[3][r]));
      vm = fmaxf(vm, __shfl_xor(vm, 1, 64));
      vm = fmaxf(vm, __shfl_xor(vm, 2, 64));
      vm = fmaxf(vm, __shfl_xor(vm, 4, 64));
      vm = fmaxf(vm, __shfl_xor(vm, 8, 64));
      const float mnew = fmaxf(mprev[r], vm);
      const float alpha = exp2f(mprev[r] - mnew);
      float rs = 0.f;
      unsigned short ph[4], pl[4];
#pragma unroll
      for (int st = 0; st < 4; st++) {
        const float p = exp2f(sf[st][r] - mnew);
        rs += p;
        const unsigned short h16 = bf16_rne(p);
        ph[st] = h16;
        pl[st] = bf16_rne(p - bf16_f(h16));
      }
      rs += __shfl_xor(rs, 1, 64);
      rs += __shfl_xor(rs, 2, 64);
      rs += __shfl_xor(rs, 4, 64);
      rs += __shfl_xor(rs, 8, 64);
      lrun[r] = lrun[r] * alpha + rs;
      mprev[r] = mnew;
#pragma unroll
      for (int dt = 0; dt < 4; dt++) Oc[dt][r] *= alpha;
      const int prow = wid * 1152 + (quad * 4 + r) * 72 + ln;
#pragma unroll
      for (int st = 0; st < 4; st++) {
        PsH[prow + st * 16] = ph[st];
        PsL[prow + st * 16] = pl[st];
      }
    }
    // ---- O += P V (split 3-term) ----
    const unsigned short* pwH = PsH + wid * 1152 + ln * 72;
    const unsigned short* pwL = PsL + wid * 1152 + ln * 72;
#pragma unroll
    for (int dt = 0; dt < 4; dt++) {
      f32x4 acc = Oc[dt];
      const unsigned short* vrH = &VsH[(dt * 16 + ln) * 72];
      const unsigned short* vrL = &VsL[(dt * 16 + ln) * 72];
#pragma unroll
      for (int ks = 0; ks < 2; ks++) {
        const bf16x8 phv = *(const bf16x8*)(pwH + ks * 32 + quad * 8);
        const bf16x8 plv = *(const bf16x8*)(pwL + ks * 32 + quad * 8);
        const bf16x8 vh = *(const bf16x8*)(vrH + ks * 32 + quad * 8);
        const bf16x8 vl = *(const bf16x8*)(vrL + ks * 32 + quad * 8);
        acc = __builtin_amdgcn_mfma_f32_16x16x32_bf16(phv, vh, acc, 0, 0, 0);
        acc = __builtin_amdgcn_mfma_f32_16x16x32_bf16(plv, vh, acc, 0, 0, 0);
        acc = __builtin_amdgcn_mfma_f32_16x16x32_bf16(phv, vl, acc, 0, 0, 0);
      }
      Oc[dt] = acc;
    }
  }
  // ---- epilogue: normalize, store ----
  float inv[4];
#pragma unroll
  for (int r = 0; r < 4; r++) inv[r] = 1.0f / lrun[r];
#pragma unroll
  for (int dt = 0; dt < 4; dt++) {
#pragma unroll
    for (int r = 0; r < 4; r++) {
      const int tok = b * cS + q0 + wid * 16 + quad * 4 + r;
      out[(size_t)tok * cD + h * cDH + dt * 16 + ln] = Oc[dt][r] * inv[r];
    }
  }
}

// ---------------------------------------------------------------------------
// Router (unchanged)
// ---------------------------------------------------------------------------
__global__ __launch_bounds__(256) void router_kernel(
    const float* __restrict__ x2, const float* __restrict__ rw,
    const float* __restrict__ rb, const unsigned char* __restrict__ pad,
    float* __restrict__ gate, int* __restrict__ eidx, float* __restrict__ Psum,
    float* __restrict__ zsum) {
  __shared__ float Pacc[8];
  __shared__ float Zacc;
  if (threadIdx.x < 8) Pacc[threadIdx.x] = 0.f;
  if (threadIdx.x == 8) Zacc = 0.f;
  __syncthreads();
  const int tid = threadIdx.x, wid = tid >> 6, lane = tid & 63;
  const int e = lane & 7, dbase = lane >> 3;
  for (int tok = blockIdx.x * 4 + wid; tok < cN; tok += gridDim.x * 4) {
    const float* xr = x2 + (size_t)tok * cD;
    float partial = 0.f;
#pragma unroll 8
    for (int i = 0; i < cD / 8; i++) {
      const int d = dbase + i * 8;
      partial += xr[d] * rw[d * 8 + e];
    }
    partial += __shfl_xor(partial, 8, 64);
    partial += __shfl_xor(partial, 16, 64);
    partial += __shfl_xor(partial, 32, 64);
    const float logit = partial + rb[e];
    float mx = logit;
    mx = fmaxf(mx, __shfl_xor(mx, 1, 64));
    mx = fmaxf(mx, __shfl_xor(mx, 2, 64));
    mx = fmaxf(mx, __shfl_xor(mx, 4, 64));
    const float ex = __expf(logit - mx);
    float sm = ex;
    sm += __shfl_xor(sm, 1, 64);
    sm += __shfl_xor(sm, 2, 64);
    sm += __shfl_xor(sm, 4, 64);
    const float prob = ex / sm;
    float bv = logit;
    int bi = e;
#pragma unroll
    for (int m = 1; m < 8; m <<= 1) {
      const float ov = __shfl_xor(bv, m, 64);
      const int oi = __shfl_xor(bi, m, 64);
      if (ov > bv || (ov == bv && oi < bi)) {
        bv = ov;
        bi = oi;
      }
    }
    const float g = __shfl(prob, (lane & 0x38) | bi, 64);
    const bool valid = (pad[tok] == 0);
    if (lane == 0) {
      eidx[tok] = bi;
      gate[tok] = g;
    }
    if (valid) {
      if (lane < 8) atomicAdd(&Pacc[lane], prob);
      if (lane == 0) {
        const float lse = mx + logf(sm);
        atomicAdd(&Zacc, lse * lse);
      }
    }
  }
  __syncthreads();
  if (threadIdx.x < 8) atomicAdd(&Psum[threadIdx.x], Pacc[threadIdx.x]);
  if (threadIdx.x == 8) atomicAdd(zsum, Zacc);
}

// ---------------------------------------------------------------------------
// Capacity scan (unchanged)
// ---------------------------------------------------------------------------
__global__ __launch_bounds__(256) void scan_kernel(const int* __restrict__ eidx,
                                                   const unsigned char* __restrict__ pad,
                                                   int* __restrict__ slot,
                                                   int* __restrict__ counts) {
  __shared__ int cnt[256][8];
  const int t = threadIdx.x;
  int lc[8] = {0, 0, 0, 0, 0, 0, 0, 0};
  const int base = t * 32;
  for (int i = 0; i < 32; i++) {
    const int tok = base + i;
    if (!pad[tok]) lc[eidx[tok]]++;
  }
#pragma unroll
  for (int e2 = 0; e2 < 8; e2++) cnt[t][e2] = lc[e2];
  __syncthreads();
  if (t < 8) {
    int run = 0;
    for (int i = 0; i < 256; i++) {
      const int v = cnt[i][t];
      cnt[i][t] = run;
      run += v;
    }
    counts[t] = run;
  }
  __syncthreads();
  int off[8];
#pragma unroll
  for (int e2 = 0; e2 < 8; e2++) off[e2] = cnt[t][e2];
  for (int i = 0; i < 32; i++) {
    const int tok = base + i;
    if (!pad[tok]) {
      const int e2 = eidx[tok];
      const int p = off[e2]++;
      slot[tok] = (p < cCAP) ? (e2 * cCAP + p) : -1;
    } else {
      slot[tok] = -1;
    }
  }
}

__global__ __launch_bounds__(256) void dispatch_kernel(const float* __restrict__ x2,
                                                       const int* __restrict__ slot,
                                                       float* __restrict__ disp) {
  const int tok = blockIdx.x;
  const int s = slot[tok];
  if (s < 0) return;
  const float4 v = ((const float4*)(x2 + (size_t)tok * cD))[threadIdx.x];
  ((float4*)(disp + (size_t)s * cD))[threadIdx.x] = v;
}

__global__ __launch_bounds__(256) void gather_kernel(const float* __restrict__ src1,
                                                     const float* __restrict__ o,
                                                     const int* __restrict__ slot,
                                                     const float* __restrict__ gate,
                                                     float* __restrict__ out) {
  const int tok = blockIdx.x;
  float4 r = ((const float4*)(src1 + (size_t)tok * cD))[threadIdx.x];
  const int s = slot[tok];
  if (s >= 0) {
    const float g = gate[tok];
    const float4 ov = ((const float4*)(o + (size_t)s * cD))[threadIdx.x];
    r.x += g * ov.x;
    r.y += g * ov.y;
    r.z += g * ov.z;
    r.w += g * ov.w;
  }
  ((float4*)(out + (size_t)tok * cD))[threadIdx.x] = r;
}

__global__ void loss_kernel(const int* __restrict__ counts,
                            const float* __restrict__ Psum,
                            const float* __restrict__ zsum,
                            float* __restrict__ out) {
  if (threadIdx.x == 0) {
    int tot = 0;
    for (int e2 = 0; e2 < 8; e2++) tot += counts[e2];
    const float denom = fmaxf((float)tot, 1.0f);
    float lp = 0.f;
    for (int e2 = 0; e2 < 8; e2++)
      lp += ((float)counts[e2] / denom) * (Psum[e2] / denom);
    out[0] = 8.0f * lp;
    out[1] = zsum[0] / denom;
  }
}

// ---------------------------------------------------------------------------
// Workspace layout (float units). Attention bf16 split arrays overlap hbuf
// (dead before FFN writes hbuf). obuf aliases dead qkv.
// ---------------------------------------------------------------------------
constexpr size_t OFF_QKV = 0;          // N*3D floats (obuf reuses)
constexpr size_t OFF_X = 25165824;     // LN1 out / attn out
constexpr size_t OFF_SRC1 = 33554432;
constexpr size_t OFF_X2 = 41943040;
constexpr size_t OFF_DISP = 50331648;  // ECAP*D
constexpr size_t OFF_H = 60817408;     // ECAP*F floats; also bf16 splits early
constexpr size_t OFF_GATE = 102760448;
constexpr size_t OFF_EIDX = 102768640;
constexpr size_t OFF_SLOT = 102776832;
constexpr size_t OFF_ACC = 102785024;

extern "C" void kernel_launch(void* const* d_in, const int* in_sizes, int n_in,
                              void* d_out, int out_size, void* d_ws, size_t ws_size,
                              hipStream_t stream) {
  (void)in_sizes; (void)n_in; (void)out_size; (void)ws_size;
  const float* src = (const float*)d_in[0];
  const unsigned char* pad = (const unsigned char*)d_in[1];
  const float* ln1_g = (const float*)d_in[2];
  const float* ln1_b = (const float*)d_in[3];
  const float* in_proj_w = (const float*)d_in[4];
  const float* in_proj_b = (const float*)d_in[5];
  const float* out_proj_w = (const float*)d_in[6];
  const float* out_proj_b = (const float*)d_in[7];
  const float* ln2_g = (const float*)d_in[8];
  const float* ln2_b = (const float*)d_in[9];
  const float* router_w = (const float*)d_in[10];
  const float* router_b = (const float*)d_in[11];
  const float* w1 = (const float*)d_in[12];
  const float* b1 = (const float*)d_in[13];
  const float* w2 = (const float*)d_in[14];
  const float* b2 = (const float*)d_in[15];
  float* out = (float*)d_out;
  float* w = (float*)d_ws;

  float* qkv = w + OFF_QKV;
  float* xbuf = w + OFF_X;
  float* src1 = w + OFF_SRC1;
  float* x2 = w + OFF_X2;
  float* disp = w + OFF_DISP;
  float* hbuf = w + OFF_H;
  float* obuf = w + OFF_QKV;
  float* gate = w + OFF_GATE;
  int* eidx = (int*)(w + OFF_EIDX);
  int* slot = (int*)(w + OFF_SLOT);
  float* Psum = w + OFF_ACC;
  float* zsum = w + OFF_ACC + 8;
  int* counts = (int*)(w + OFF_ACC + 16);

  // bf16 split arrays (u16 units), overlapping hbuf region
  unsigned short* usp = (unsigned short*)(w + OFF_H);
  constexpr size_t SPN = (size_t)cN * cD;  // 8388608 per array
  unsigned short* Qh = usp + 0 * SPN;
  unsigned short* Ql = usp + 1 * SPN;
  unsigned short* Kh = usp + 2 * SPN;
  unsigned short* Kl = usp + 3 * SPN;
  unsigned short* Vth = usp + 4 * SPN;
  unsigned short* Vtl = usp + 5 * SPN;

  hipMemsetAsync(Psum, 0, 9 * sizeof(float), stream);

  // 1) LN1
  ln_kernel<<<cN, 256, 0, stream>>>(src, ln1_g, ln1_b, xbuf);
  // 2) QKV projection (fp32)
  gemm128<0, false, false><<<dim3(24, 64, 1), 256, 0, stream>>>(
      xbuf, 0, in_proj_w, 0, in_proj_b, 0, nullptr, qkv, 0,
      cN, 3 * cD, cD, cD, cD, 3 * cD);
  // 2.5) split into bf16 hi/lo (+ V transpose)
  qkv_split_kernel<<<dim3(cS / 64, cH, cB), 256, 0, stream>>>(
      qkv, Qh, Ql, Kh, Kl, Vth, Vtl);
  // 3) MFMA flash attention -> xbuf
  attn_mfma_kernel<<<dim3(cS / 64, cH, cB), 256, 0, stream>>>(
      Qh, Ql, Kh, Kl, Vth, Vtl, pad, xbuf);
  // 4) out_proj + residual(src) -> src1
  gemm128<0, false, true><<<dim3(8, 64, 1), 256, 0, stream>>>(
      xbuf, 0, out_proj_w, 0, out_proj_b, 0, src, src1, 0,
      cN, cD, cD, cD, cD, cD);
  // 5) LN2
  ln_kernel<<<cN, 256, 0, stream>>>(src1, ln2_g, ln2_b, x2);
  // 6) router
  router_kernel<<<256, 256, 0, stream>>>(x2, router_w, router_b, pad, gate, eidx,
                                         Psum, zsum);
  // 7) capacity scan
  scan_kernel<<<1, 256, 0, stream>>>(eidx, pad, slot, counts);
  // 8) dispatch scatter
  dispatch_kernel<<<cN, 256, 0, stream>>>(x2, slot, disp);
  // 9) expert FFN layer 1 (fp32)
  gemm128<1, true, false><<<dim3(32, 10, 8), 256, 0, stream>>>(
      disp, (size_t)cCAP * cD, w1, (size_t)cD * cF, b1, (size_t)cF, nullptr,
      hbuf, (size_t)cCAP * cF, cCAP, cF, cD, cD, cF, cF);
  // 10) expert FFN layer 2 (fp32)
  gemm128<1, false, false><<<dim3(8, 10, 8), 256, 0, stream>>>(
      hbuf, (size_t)cCAP * cF, w2, (size_t)cF * cD, b2, (size_t)cD, nullptr,
      obuf, (size_t)cCAP * cD, cCAP, cD, cF, cF, cD, cD);
  // 11) gather + residual -> out
  gather_kernel<<<cN, 256, 0, stream>>>(src1, obuf, slot, gate, out);
  // 12) losses
  loss_kernel<<<1, 64, 0, stream>>>(counts, Psum, zsum, out + (size_t)cN * cD);
}

// Round 3
// 1488.136 us; speedup vs baseline: 3.8092x; 2.4425x over previous
//
#include <hip/hip_runtime.h>

// Problem constants
constexpr int cB = 4, cS = 2048, cD = 1024, cH = 16, cE = 8, cF = 4096;
constexpr int cN = cB * cS;          // 8192 tokens
constexpr int cDH = 64;
constexpr int cCAP = 1280;           // int(1.25 * 8192 / 8)
constexpr int cECAP = cE * cCAP;     // 10240

typedef __attribute__((ext_vector_type(8))) short bf16x8;
typedef __attribute__((ext_vector_type(4))) float f32x4;
typedef __attribute__((ext_vector_type(4))) unsigned short u16x4;

__device__ inline unsigned short bf16_rne(float x) {
  unsigned u = __float_as_uint(x);
  u += 0x7FFF + ((u >> 16) & 1);
  return (unsigned short)(u >> 16);
}
__device__ inline float bf16_f(unsigned short h) {
  return __uint_as_float(((unsigned)h) << 16);
}

// ---------------------------------------------------------------------------
// LayerNorm fp32 (LN2): one block per token.
// ---------------------------------------------------------------------------
__global__ __launch_bounds__(256) void ln_kernel(const float* __restrict__ x,
                                                 const float* __restrict__ g,
                                                 const float* __restrict__ bb,
                                                 float* __restrict__ y) {
  __shared__ float red[8];
  const int row = blockIdx.x;
  const int t = threadIdx.x;
  const float4 v = ((const float4*)(x + (size_t)row * cD))[t];
  float s = v.x + v.y + v.z + v.w;
#pragma unroll
  for (int m = 32; m >= 1; m >>= 1) s += __shfl_xor(s, m, 64);
  if ((t & 63) == 0) red[t >> 6] = s;
  __syncthreads();
  const float mean = (red[0] + red[1] + red[2] + red[3]) * (1.0f / cD);
  const float dx = v.x - mean, dy = v.y - mean, dz = v.z - mean, dw = v.w - mean;
  float ss = dx * dx + dy * dy + dz * dz + dw * dw;
#pragma unroll
  for (int m = 32; m >= 1; m >>= 1) ss += __shfl_xor(ss, m, 64);
  if ((t & 63) == 0) red[4 + (t >> 6)] = ss;
  __syncthreads();
  const float var = (red[4] + red[5] + red[6] + red[7]) * (1.0f / cD);
  const float inv = rsqrtf(var + 1e-5f);
  const float4 gg = ((const float4*)g)[t];
  const float4 b4 = ((const float4*)bb)[t];
  float4 o;
  o.x = dx * inv * gg.x + b4.x;
  o.y = dy * inv * gg.y + b4.y;
  o.z = dz * inv * gg.z + b4.z;
  o.w = dw * inv * gg.w + b4.w;
  ((float4*)(y + (size_t)row * cD))[t] = o;
}

// ---------------------------------------------------------------------------
// LayerNorm with split-bf16 output (LN1 -> QKV GEMM A operand).
// ---------------------------------------------------------------------------
__global__ __launch_bounds__(256) void ln_split_kernel(
    const float* __restrict__ x, const float* __restrict__ g,
    const float* __restrict__ bb, unsigned short* __restrict__ yh,
    unsigned short* __restrict__ yl) {
  __shared__ float red[8];
  const int row = blockIdx.x;
  const int t = threadIdx.x;
  const float4 v = ((const float4*)(x + (size_t)row * cD))[t];
  float s = v.x + v.y + v.z + v.w;
#pragma unroll
  for (int m = 32; m >= 1; m >>= 1) s += __shfl_xor(s, m, 64);
  if ((t & 63) == 0) red[t >> 6] = s;
  __syncthreads();
  const float mean = (red[0] + red[1] + red[2] + red[3]) * (1.0f / cD);
  const float dx = v.x - mean, dy = v.y - mean, dz = v.z - mean, dw = v.w - mean;
  float ss = dx * dx + dy * dy + dz * dz + dw * dw;
#pragma unroll
  for (int m = 32; m >= 1; m >>= 1) ss += __shfl_xor(ss, m, 64);
  if ((t & 63) == 0) red[4 + (t >> 6)] = ss;
  __syncthreads();
  const float var = (red[4] + red[5] + red[6] + red[7]) * (1.0f / cD);
  const float inv = rsqrtf(var + 1e-5f);
  const float4 gg = ((const float4*)g)[t];
  const float4 b4 = ((const float4*)bb)[t];
  const float oa[4] = {dx * inv * gg.x + b4.x, dy * inv * gg.y + b4.y,
                       dz * inv * gg.z + b4.z, dw * inv * gg.w + b4.w};
  u16x4 hh, ll;
#pragma unroll
  for (int i = 0; i < 4; i++) {
    const unsigned short h16 = bf16_rne(oa[i]);
    hh[i] = h16;
    ll[i] = bf16_rne(oa[i] - bf16_f(h16));
  }
  *(u16x4*)(yh + (size_t)row * cD + t * 4) = hh;
  *(u16x4*)(yl + (size_t)row * cD + t * 4) = ll;
}

// ---------------------------------------------------------------------------
// Weight split: fp32 -> bf16 hi/lo, same layout. n4 = element_count/4.
// ---------------------------------------------------------------------------
__global__ __launch_bounds__(256) void wsplit_kernel(const float* __restrict__ in,
                                                     unsigned short* __restrict__ hi,
                                                     unsigned short* __restrict__ lo,
                                                     int n4) {
  const int i = blockIdx.x * 256 + threadIdx.x;
  if (i >= n4) return;
  const float4 v = ((const float4*)in)[i];
  const float a[4] = {v.x, v.y, v.z, v.w};
  u16x4 hh, ll;
#pragma unroll
  for (int j = 0; j < 4; j++) {
    const unsigned short h16 = bf16_rne(a[j]);
    hh[j] = h16;
    ll[j] = bf16_rne(a[j] - bf16_f(h16));
  }
  *(u16x4*)(hi + (size_t)i * 4) = hh;
  *(u16x4*)(lo + (size_t)i * 4) = ll;
}

// ---------------------------------------------------------------------------
// Transpose + bf16 convert: in fp32 [z][R][C] -> out bf16 [z][C][R].
// 64x64 tiles via LDS. grid (C/64, R/64, Z).
// ---------------------------------------------------------------------------
__global__ __launch_bounds__(256) void transpose_bf16_kernel(
    const float* __restrict__ in, unsigned short* __restrict__ outp, int Rr,
    int Cc) {
  __shared__ float T[64][65];
  const int z = blockIdx.z;
  in += (size_t)z * Rr * Cc;
  outp += (size_t)z * Rr * Cc;
  const int c0 = blockIdx.x * 64, r0 = blockIdx.y * 64;
  const int tid = threadIdx.x;
#pragma unroll
  for (int u = 0; u < 4; u++) {
    const int a = tid + u * 256;
    const int r = a >> 4, c4 = (a & 15) << 2;
    const float4 v = *(const float4*)(in + (size_t)(r0 + r) * Cc + c0 + c4);
    T[r][c4 + 0] = v.x;
    T[r][c4 + 1] = v.y;
    T[r][c4 + 2] = v.z;
    T[r][c4 + 3] = v.w;
  }
  __syncthreads();
#pragma unroll
  for (int u = 0; u < 4; u++) {
    const int a = tid + u * 256;
    const int c = a >> 4, r4 = (a & 15) << 2;
    u16x4 o;
#pragma unroll
    for (int i = 0; i < 4; i++) o[i] = bf16_rne(T[r4 + i][c]);
    *(u16x4*)(outp + (size_t)(c0 + c) * Rr + r0 + r4) = o;
  }
}

// ---------------------------------------------------------------------------
// bf16 MFMA GEMM: C[M,N] = A[M,K] * B[N,K]^T + bias (+relu)(+fp32 resid).
// A,B bf16 [row][K]; SPLIT adds lo arrays for 3-term ~fp32 fidelity.
// 128x128 tile, BK=32, 4 waves each 64x64 (4x4 of 16x16x32 MFMA).
// LDS rows padded to 40 u16 (80 B) -> frag b128 reads 2-way (free).
// mfma_f32_16x16x32_bf16 layouts (verified): A/B frag idx=lane&15,
// k=quad*8+j; D col(n)=lane&15, row(m)=quad*4+reg.
// ---------------------------------------------------------------------------
template <bool SPLIT, bool RELU, bool RESID, bool OUTBF16>
__global__ __launch_bounds__(256) void gemm_bf16(
    const unsigned short* __restrict__ Ah, const unsigned short* __restrict__ Al,
    size_t sA,
    const unsigned short* __restrict__ Bh, const unsigned short* __restrict__ Bl,
    size_t sB,
    const float* __restrict__ bias, size_t sBias,
    const float* __restrict__ R,
    void* __restrict__ Cv, size_t sC,
    int K, int lda, int ldb, int ldc) {
  __shared__ unsigned short AsH[128 * 40];
  __shared__ unsigned short BsH[128 * 40];
  __shared__ unsigned short AsL[SPLIT ? 128 * 40 : 8];
  __shared__ unsigned short BsL[SPLIT ? 128 * 40 : 8];
  const int z = blockIdx.z;
  Ah += (size_t)z * sA;
  Bh += (size_t)z * sB;
  if constexpr (SPLIT) {
    Al += (size_t)z * sA;
    Bl += (size_t)z * sB;
  }
  bias += (size_t)z * sBias;
  const int n0 = blockIdx.x * 128, m0 = blockIdx.y * 128;
  const int tid = threadIdx.x;
  const int wid = tid >> 6, lane = tid & 63;
  const int ln = lane & 15, quad = lane >> 4;
  const int wm = (wid >> 1) * 64, wn = (wid & 1) * 64;

  f32x4 acc[4][4];
#pragma unroll
  for (int i = 0; i < 4; i++)
#pragma unroll
    for (int j = 0; j < 4; j++) acc[i][j] = (f32x4){0.f, 0.f, 0.f, 0.f};

  for (int k0 = 0; k0 < K; k0 += 32) {
    __syncthreads();
#pragma unroll
    for (int u = 0; u < 2; u++) {
      const int c = tid + u * 256;           // 0..511
      const int row = c >> 2, ko = (c & 3) << 3;
      const int ld = row * 40 + ko;
      *(uint4*)&AsH[ld] = *(const uint4*)(Ah + (size_t)(m0 + row) * lda + k0 + ko);
      *(uint4*)&BsH[ld] = *(const uint4*)(Bh + (size_t)(n0 + row) * ldb + k0 + ko);
      if constexpr (SPLIT) {
        *(uint4*)&AsL[ld] = *(const uint4*)(Al + (size_t)(m0 + row) * lda + k0 + ko);
        *(uint4*)&BsL[ld] = *(const uint4*)(Bl + (size_t)(n0 + row) * ldb + k0 + ko);
      }
    }
    __syncthreads();
    bf16x8 bh[4], bl[4];
#pragma unroll
    for (int nt = 0; nt < 4; nt++) {
      bh[nt] = *(const bf16x8*)&BsH[(wn + nt * 16 + ln) * 40 + quad * 8];
      if constexpr (SPLIT)
        bl[nt] = *(const bf16x8*)&BsL[(wn + nt * 16 + ln) * 40 + quad * 8];
    }
#pragma unroll
    for (int mt = 0; mt < 4; mt++) {
      const bf16x8 ah = *(const bf16x8*)&AsH[(wm + mt * 16 + ln) * 40 + quad * 8];
      bf16x8 al;
      if constexpr (SPLIT)
        al = *(const bf16x8*)&AsL[(wm + mt * 16 + ln) * 40 + quad * 8];
#pragma unroll
      for (int nt = 0; nt < 4; nt++) {
        acc[mt][nt] =
            __builtin_amdgcn_mfma_f32_16x16x32_bf16(ah, bh[nt], acc[mt][nt], 0, 0, 0);
        if constexpr (SPLIT) {
          acc[mt][nt] =
              __builtin_amdgcn_mfma_f32_16x16x32_bf16(al, bh[nt], acc[mt][nt], 0, 0, 0);
          acc[mt][nt] =
              __builtin_amdgcn_mfma_f32_16x16x32_bf16(ah, bl[nt], acc[mt][nt], 0, 0, 0);
        }
      }
    }
  }
  // epilogue
  float* Cf = nullptr;
  unsigned short* Cb = nullptr;
  if constexpr (OUTBF16)
    Cb = (unsigned short*)Cv + (size_t)z * sC;
  else
    Cf = (float*)Cv + (size_t)z * sC;
#pragma unroll
  for (int mt = 0; mt < 4; mt++) {
#pragma unroll
    for (int nt = 0; nt < 4; nt++) {
      const int col = n0 + wn + nt * 16 + ln;
      const float bv = bias[col];
#pragma unroll
      for (int r = 0; r < 4; r++) {
        const int row = m0 + wm + mt * 16 + quad * 4 + r;
        float v = acc[mt][nt][r] + bv;
        if constexpr (RELU) v = fmaxf(v, 0.f);
        if constexpr (RESID) v += R[(size_t)row * ldc + col];
        if constexpr (OUTBF16)
          Cb[(size_t)row * ldc + col] = bf16_rne(v);
        else
          Cf[(size_t)row * ldc + col] = v;
      }
    }
  }
}

// ---------------------------------------------------------------------------
// Pre-pass: split fp32 qkv into bf16 hi/lo arrays for MFMA attention.
// Q,K -> [b,h,s,64]; V -> transposed [b,h,64,s] (via LDS).
// ---------------------------------------------------------------------------
__global__ __launch_bounds__(256) void qkv_split_kernel(
    const float* __restrict__ qkv,
    unsigned short* __restrict__ Qh, unsigned short* __restrict__ Ql,
    unsigned short* __restrict__ Kh, unsigned short* __restrict__ Kl,
    unsigned short* __restrict__ Vth, unsigned short* __restrict__ Vtl) {
  __shared__ float Vs[64 * 66];
  const int s0 = blockIdx.x << 6;
  const int h = blockIdx.y, b = blockIdx.z;
  const int tid = threadIdx.x;
  const size_t qkbase = ((size_t)(b * cH + h) * cS + s0) * cDH;
  const size_t vtbase = (size_t)(b * cH + h) * cDH * cS + s0;
#pragma unroll
  for (int u = 0; u < 4; u++) {
    const int a = tid + u * 256;          // 0..1023
    const int r = a >> 4, c4 = (a & 15) << 2;
    const float* rowp = qkv + (size_t)(b * cS + s0 + r) * (3 * cD) + h * cDH + c4;
    const float4 qv = *(const float4*)(rowp);
    const float4 kv = *(const float4*)(rowp + cD);
    const float4 vv = *(const float4*)(rowp + 2 * cD);
    u16x4 hq, lq, hk, lk;
    const float qa[4] = {qv.x, qv.y, qv.z, qv.w};
    const float ka[4] = {kv.x, kv.y, kv.z, kv.w};
    const float va[4] = {vv.x, vv.y, vv.z, vv.w};
#pragma unroll
    for (int i = 0; i < 4; i++) {
      const unsigned short h16 = bf16_rne(qa[i]);
      hq[i] = h16;
      lq[i] = bf16_rne(qa[i] - bf16_f(h16));
      const unsigned short h17 = bf16_rne(ka[i]);
      hk[i] = h17;
      lk[i] = bf16_rne(ka[i] - bf16_f(h17));
      Vs[(c4 + i) * 66 + r] = va[i];
    }
    *(u16x4*)(Qh + qkbase + (size_t)r * cDH + c4) = hq;
    *(u16x4*)(Ql + qkbase + (size_t)r * cDH + c4) = lq;
    *(u16x4*)(Kh + qkbase + (size_t)r * cDH + c4) = hk;
    *(u16x4*)(Kl + qkbase + (size_t)r * cDH + c4) = lk;
  }
  __syncthreads();
#pragma unroll
  for (int u = 0; u < 4; u++) {
    const int a = tid + u * 256;
    const int dh = a >> 4, k4 = (a & 15) << 2;
    u16x4 hv, lv;
#pragma unroll
    for (int i = 0; i < 4; i++) {
      const float x = Vs[dh * 66 + k4 + i];
      const unsigned short h16 = bf16_rne(x);
      hv[i] = h16;
      lv[i] = bf16_rne(x - bf16_f(h16));
    }
    *(u16x4*)(Vth + vtbase + (size_t)dh * cS + k4) = hv;
    *(u16x4*)(Vtl + vtbase + (size_t)dh * cS + k4) = lv;
  }
}

// ---------------------------------------------------------------------------
// Flash attention, split-bf16 MFMA (unchanged core); epilogue writes split
// bf16 hi/lo for the out_proj GEMM A operand.
// ---------------------------------------------------------------------------
__global__ __launch_bounds__(256) void attn_mfma_kernel(
    const unsigned short* __restrict__ Qh, const unsigned short* __restrict__ Ql,
    const unsigned short* __restrict__ Kh, const unsigned short* __restrict__ Kl,
    const unsigned short* __restrict__ Vth, const unsigned short* __restrict__ Vtl,
    const unsigned char* __restrict__ pad, unsigned short* __restrict__ Oh,
    unsigned short* __restrict__ Ol) {
  __shared__ unsigned short KsH[64 * 72];
  __shared__ unsigned short KsL[64 * 72];
  __shared__ unsigned short VsH[64 * 72];
  __shared__ unsigned short VsL[64 * 72];
  __shared__ unsigned short PsH[4 * 16 * 72];
  __shared__ unsigned short PsL[4 * 16 * 72];
  __shared__ float Mk[64];

  const int q0 = blockIdx.x << 6;
  const int h = blockIdx.y, b = blockIdx.z;
  const int tid = threadIdx.x;
  const int wid = tid >> 6, lane = tid & 63;
  const int ln = lane & 15, quad = lane >> 4;
  constexpr float SC2 = 0.125f * 1.4426950408889634f;

  const size_t bh = (size_t)(b * cH + h);
  const unsigned short* gKh = Kh + bh * cS * cDH;
  const unsigned short* gKl = Kl + bh * cS * cDH;
  const unsigned short* gVh = Vth + bh * cDH * cS;
  const unsigned short* gVl = Vtl + bh * cDH * cS;

  const size_t qbase = (bh * cS + q0 + wid * 16 + ln) * cDH;
  bf16x8 qh[2], ql[2];
#pragma unroll
  for (int ks = 0; ks < 2; ks++) {
    qh[ks] = *(const bf16x8*)(Qh + qbase + ks * 32 + quad * 8);
    ql[ks] = *(const bf16x8*)(Ql + qbase + ks * 32 + quad * 8);
  }

  f32x4 Oc[4];
  float mprev[4], lrun[4];
#pragma unroll
  for (int dt = 0; dt < 4; dt++) Oc[dt] = (f32x4){0.f, 0.f, 0.f, 0.f};
#pragma unroll
  for (int r = 0; r < 4; r++) {
    mprev[r] = -1e30f;
    lrun[r] = 0.f;
  }

  for (int kt = 0; kt < cS / 64; kt++) {
    const int k0 = kt << 6;
    __syncthreads();
#pragma unroll
    for (int u = 0; u < 2; u++) {
      const int a = tid + (u << 8);
      const int row = a >> 3, c8 = (a & 7) << 3;
      const int ld = row * 72 + c8;
      *(uint4*)&KsH[ld] = *(const uint4*)(gKh + (size_t)(k0 + row) * cDH + c8);
      *(uint4*)&KsL[ld] = *(const uint4*)(gKl + (size_t)(k0 + row) * cDH + c8);
      *(uint4*)&VsH[ld] = *(const uint4*)(gVh + (size_t)row * cS + k0 + c8);
      *(uint4*)&VsL[ld] = *(const uint4*)(gVl + (size_t)row * cS + k0 + c8);
    }
    if (tid < 64) Mk[tid] = pad[b * cS + k0 + tid] ? -1e30f : 0.0f;
    __syncthreads();

    f32x4 sac[4];
#pragma unroll
    for (int st = 0; st < 4; st++) {
      f32x4 acc = (f32x4){0.f, 0.f, 0.f, 0.f};
      const unsigned short* krH = &KsH[(st * 16 + ln) * 72];
      const unsigned short* krL = &KsL[(st * 16 + ln) * 72];
#pragma unroll
      for (int ks = 0; ks < 2; ks++) {
        const bf16x8 kh = *(const bf16x8*)(krH + ks * 32 + quad * 8);
        const bf16x8 kl = *(const bf16x8*)(krL + ks * 32 + quad * 8);
        acc = __builtin_amdgcn_mfma_f32_16x16x32_bf16(qh[ks], kh, acc, 0, 0, 0);
        acc = __builtin_amdgcn_mfma_f32_16x16x32_bf16(ql[ks], kh, acc, 0, 0, 0);
        acc = __builtin_amdgcn_mfma_f32_16x16x32_bf16(qh[ks], kl, acc, 0, 0, 0);
      }
      sac[st] = acc;
    }
    float sf[4][4];
#pragma unroll
    for (int st = 0; st < 4; st++) {
      const float ma = Mk[st * 16 + ln];
#pragma unroll
      for (int r = 0; r < 4; r++) sf[st][r] = sac[st][r] * SC2 + ma;
    }
#pragma unroll
    for (int r = 0; r < 4; r++) {
      float vm = fmaxf(fmaxf(sf[0][r], sf[1][r]), fmaxf(sf[2][r], sf[3][r]));
      vm = fmaxf(vm, __shfl_xor(vm, 1, 64));
      vm = fmaxf(vm, __shfl_xor(vm, 2, 64));
      vm = fmaxf(vm, __shfl_xor(vm, 4, 64));
      vm = fmaxf(vm, __shfl_xor(vm, 8, 64));
      const float mnew = fmaxf(mprev[r], vm);
      const float alpha = exp2f(mprev[r] - mnew);
      float rs = 0.f;
      unsigned short ph[4], pl[4];
#pragma unroll
      for (int st = 0; st < 4; st++) {
        const float p = exp2f(sf[st][r] - mnew);
        rs += p;
        const unsigned short h16 = bf16_rne(p);
        ph[st] = h16;
        pl[st] = bf16_rne(p - bf16_f(h16));
      }
      rs += __shfl_xor(rs, 1, 64);
      rs += __shfl_xor(rs, 2, 64);
      rs += __shfl_xor(rs, 4, 64);
      rs += __shfl_xor(rs, 8, 64);
      lrun[r] = lrun[r] * alpha + rs;
      mprev[r] = mnew;
#pragma unroll
      for (int dt = 0; dt < 4; dt++) Oc[dt][r] *= alpha;
      const int prow = wid * 1152 + (quad * 4 + r) * 72 + ln;
#pragma unroll
      for (int st = 0; st < 4; st++) {
        PsH[prow + st * 16] = ph[st];
        PsL[prow + st * 16] = pl[st];
      }
    }
    const unsigned short* pwH = PsH + wid * 1152 + ln * 72;
    const unsigned short* pwL = PsL + wid * 1152 + ln * 72;
#pragma unroll
    for (int dt = 0; dt < 4; dt++) {
      f32x4 acc = Oc[dt];
      const unsigned short* vrH = &VsH[(dt * 16 + ln) * 72];
      const unsigned short* vrL = &VsL[(dt * 16 + ln) * 72];
#pragma unroll
      for (int ks = 0; ks < 2; ks++) {
        const bf16x8 phv = *(const bf16x8*)(pwH + ks * 32 + quad * 8);
        const bf16x8 plv = *(const bf16x8*)(pwL + ks * 32 + quad * 8);
        const bf16x8 vh = *(const bf16x8*)(vrH + ks * 32 + quad * 8);
        const bf16x8 vl = *(const bf16x8*)(vrL + ks * 32 + quad * 8);
        acc = __builtin_amdgcn_mfma_f32_16x16x32_bf16(phv, vh, acc, 0, 0, 0);
        acc = __builtin_amdgcn_mfma_f32_16x16x32_bf16(plv, vh, acc, 0, 0, 0);
        acc = __builtin_amdgcn_mfma_f32_16x16x32_bf16(phv, vl, acc, 0, 0, 0);
      }
      Oc[dt] = acc;
    }
  }
  float inv[4];
#pragma unroll
  for (int r = 0; r < 4; r++) inv[r] = 1.0f / lrun[r];
#pragma unroll
  for (int dt = 0; dt < 4; dt++) {
#pragma unroll
    for (int r = 0; r < 4; r++) {
      const int tok = b * cS + q0 + wid * 16 + quad * 4 + r;
      const float v = Oc[dt][r] * inv[r];
      const unsigned short h16 = bf16_rne(v);
      const size_t idx = (size_t)tok * cD + h * cDH + dt * 16 + ln;
      Oh[idx] = h16;
      Ol[idx] = bf16_rne(v - bf16_f(h16));
    }
  }
}

// ---------------------------------------------------------------------------
// Router (fp32 exact — feeds the discontinuous argmax).
// ---------------------------------------------------------------------------
__global__ __launch_bounds__(256) void router_kernel(
    const float* __restrict__ x2, const float* __restrict__ rw,
    const float* __restrict__ rb, const unsigned char* __restrict__ pad,
    float* __restrict__ gate, int* __restrict__ eidx, float* __restrict__ Psum,
    float* __restrict__ zsum) {
  __shared__ float Pacc[8];
  __shared__ float Zacc;
  if (threadIdx.x < 8) Pacc[threadIdx.x] = 0.f;
  if (threadIdx.x == 8) Zacc = 0.f;
  __syncthreads();
  const int tid = threadIdx.x, wid = tid >> 6, lane = tid & 63;
  const int e = lane & 7, dbase = lane >> 3;
  for (int tok = blockIdx.x * 4 + wid; tok < cN; tok += gridDim.x * 4) {
    const float* xr = x2 + (size_t)tok * cD;
    float partial = 0.f;
#pragma unroll 8
    for (int i = 0; i < cD / 8; i++) {
      const int d = dbase + i * 8;
      partial += xr[d] * rw[d * 8 + e];
    }
    partial += __shfl_xor(partial, 8, 64);
    partial += __shfl_xor(partial, 16, 64);
    partial += __shfl_xor(partial, 32, 64);
    const float logit = partial + rb[e];
    float mx = logit;
    mx = fmaxf(mx, __shfl_xor(mx, 1, 64));
    mx = fmaxf(mx, __shfl_xor(mx, 2, 64));
    mx = fmaxf(mx, __shfl_xor(mx, 4, 64));
    const float ex = __expf(logit - mx);
    float sm = ex;
    sm += __shfl_xor(sm, 1, 64);
    sm += __shfl_xor(sm, 2, 64);
    sm += __shfl_xor(sm, 4, 64);
    const float prob = ex / sm;
    float bv = logit;
    int bi = e;
#pragma unroll
    for (int m = 1; m < 8; m <<= 1) {
      const float ov = __shfl_xor(bv, m, 64);
      const int oi = __shfl_xor(bi, m, 64);
      if (ov > bv || (ov == bv && oi < bi)) {
        bv = ov;
        bi = oi;
      }
    }
    const float g = __shfl(prob, (lane & 0x38) | bi, 64);
    const bool valid = (pad[tok] == 0);
    if (lane == 0) {
      eidx[tok] = bi;
      gate[tok] = g;
    }
    if (valid) {
      if (lane < 8) atomicAdd(&Pacc[lane], prob);
      if (lane == 0) {
        const float lse = mx + logf(sm);
        atomicAdd(&Zacc, lse * lse);
      }
    }
  }
  __syncthreads();
  if (threadIdx.x < 8) atomicAdd(&Psum[threadIdx.x], Pacc[threadIdx.x]);
  if (threadIdx.x == 8) atomicAdd(zsum, Zacc);
}

// ---------------------------------------------------------------------------
// Capacity scan (unchanged).
// ---------------------------------------------------------------------------
__global__ __launch_bounds__(256) void scan_kernel(const int* __restrict__ eidx,
                                                   const unsigned char* __restrict__ pad,
                                                   int* __restrict__ slot,
                                                   int* __restrict__ counts) {
  __shared__ int cnt[256][8];
  const int t = threadIdx.x;
  int lc[8] = {0, 0, 0, 0, 0, 0, 0, 0};
  const int base = t * 32;
  for (int i = 0; i < 32; i++) {
    const int tok = base + i;
    if (!pad[tok]) lc[eidx[tok]]++;
  }
#pragma unroll
  for (int e2 = 0; e2 < 8; e2++) cnt[t][e2] = lc[e2];
  __syncthreads();
  if (t < 8) {
    int run = 0;
    for (int i = 0; i < 256; i++) {
      const int v = cnt[i][t];
      cnt[i][t] = run;
      run += v;
    }
    counts[t] = run;
  }
  __syncthreads();
  int off[8];
#pragma unroll
  for (int e2 = 0; e2 < 8; e2++) off[e2] = cnt[t][e2];
  for (int i = 0; i < 32; i++) {
    const int tok = base + i;
    if (!pad[tok]) {
      const int e2 = eidx[tok];
      const int p = off[e2]++;
      slot[tok] = (p < cCAP) ? (e2 * cCAP + p) : -1;
    } else {
      slot[tok] = -1;
    }
  }
}

__global__ __launch_bounds__(256) void dispatch_bf16_kernel(
    const float* __restrict__ x2, const int* __restrict__ slot,
    unsigned short* __restrict__ disp) {
  const int tok = blockIdx.x;
  const int s = slot[tok];
  if (s < 0) return;
  const float4 v = ((const float4*)(x2 + (size_t)tok * cD))[threadIdx.x];
  u16x4 o;
  o[0] = bf16_rne(v.x);
  o[1] = bf16_rne(v.y);
  o[2] = bf16_rne(v.z);
  o[3] = bf16_rne(v.w);
  *(u16x4*)(disp + (size_t)s * cD + threadIdx.x * 4) = o;
}

__global__ __launch_bounds__(256) void gather_kernel(const float* __restrict__ src1,
                                                     const float* __restrict__ o,
                                                     const int* __restrict__ slot,
                                                     const float* __restrict__ gate,
                                                     float* __restrict__ out) {
  const int tok = blockIdx.x;
  float4 r = ((const float4*)(src1 + (size_t)tok * cD))[threadIdx.x];
  const int s = slot[tok];
  if (s >= 0) {
    const float g = gate[tok];
    const float4 ov = ((const float4*)(o + (size_t)s * cD))[threadIdx.x];
    r.x += g * ov.x;
    r.y += g * ov.y;
    r.z += g * ov.z;
    r.w += g * ov.w;
  }
  ((float4*)(out + (size_t)tok * cD))[threadIdx.x] = r;
}

__global__ void loss_kernel(const int* __restrict__ counts,
                            const float* __restrict__ Psum,
                            const float* __restrict__ zsum,
                            float* __restrict__ out) {
  if (threadIdx.x == 0) {
    int tot = 0;
    for (int e2 = 0; e2 < 8; e2++) tot += counts[e2];
    const float denom = fmaxf((float)tot, 1.0f);
    float lp = 0.f;
    for (int e2 = 0; e2 < 8; e2++)
      lp += ((float)counts[e2] / denom) * (Psum[e2] / denom);
    out[0] = 8.0f * lp;
    out[1] = zsum[0] / denom;
  }
}

// ---------------------------------------------------------------------------
// Workspace layout (float units), sequential lifetimes:
// R_A: qkv fp32 (QKV gemm->qkv_split) / w1t bf16 (->FFN1) / w2t bf16 (->FFN2)
// R_B: Q..Vt splits (qkv_split->attn) / h bf16 (FFN1->FFN2)
// R_XHL: xh+xl (LN1->QKV) / Oh+Ol (attn->out_proj) / disp bf16 (dispatch->FFN1)
// R_X2O: x2 (LN2->dispatch) / obuf fp32 (FFN2->gather)
// Total ~327 MB (< 411 MB proven in round 0).
// ---------------------------------------------------------------------------
constexpr size_t OFF_A = 0;              // 25,165,824 floats
constexpr size_t OFF_B = 25165824;       // 25,165,824
constexpr size_t OFF_XHL = 50331648;     // 8,388,608
constexpr size_t OFF_SRC1 = 58720256;    // 8,388,608
constexpr size_t OFF_X2O = 67108864;     // 10,485,760
constexpr size_t OFF_IPW = 77594624;     // 3,145,728
constexpr size_t OFF_OPW = 80740352;     // 1,048,576
constexpr size_t OFF_MISC = 81788928;

extern "C" void kernel_launch(void* const* d_in, const int* in_sizes, int n_in,
                              void* d_out, int out_size, void* d_ws, size_t ws_size,
                              hipStream_t stream) {
  (void)in_sizes; (void)n_in; (void)out_size; (void)ws_size;
  const float* src = (const float*)d_in[0];
  const unsigned char* pad = (const unsigned char*)d_in[1];
  const float* ln1_g = (const float*)d_in[2];
  const float* ln1_b = (const float*)d_in[3];
  const float* in_proj_w = (const float*)d_in[4];
  const float* in_proj_b = (const float*)d_in[5];
  const float* out_proj_w = (const float*)d_in[6];
  const float* out_proj_b = (const float*)d_in[7];
  const float* ln2_g = (const float*)d_in[8];
  const float* ln2_b = (const float*)d_in[9];
  const float* router_w = (const float*)d_in[10];
  const float* router_b = (const float*)d_in[11];
  const float* w1 = (const float*)d_in[12];
  const float* b1 = (const float*)d_in[13];
  const float* w2 = (const float*)d_in[14];
  const float* b2 = (const float*)d_in[15];
  float* out = (float*)d_out;
  float* w = (float*)d_ws;

  float* qkv = w + OFF_A;
  unsigned short* w1t = (unsigned short*)(w + OFF_A);   // after qkv dead
  unsigned short* w2t = (unsigned short*)(w + OFF_A);   // after w1t dead
  unsigned short* usB = (unsigned short*)(w + OFF_B);
  constexpr size_t SPN = (size_t)cN * cD;               // 8,388,608 u16
  unsigned short* Qh = usB + 0 * SPN;
  unsigned short* Ql = usB + 1 * SPN;
  unsigned short* Kh = usB + 2 * SPN;
  unsigned short* Kl = usB + 3 * SPN;
  unsigned short* Vth = usB + 4 * SPN;
  unsigned short* Vtl = usB + 5 * SPN;
  unsigned short* hbuf16 = usB;                          // after splits dead
  unsigned short* xh = (unsigned short*)(w + OFF_XHL);
  unsigned short* xl = xh + SPN;
  unsigned short* Oh = xh;                               // after xh/xl dead
  unsigned short* Ol = xh + SPN;
  unsigned short* disp16 = xh;                           // after Oh/Ol dead
  float* src1 = w + OFF_SRC1;
  float* x2 = w + OFF_X2O;
  float* obuf = w + OFF_X2O;                             // after x2 dead
  unsigned short* ipwh = (unsigned short*)(w + OFF_IPW);
  unsigned short* ipwl = ipwh + (size_t)3 * cD * cD;
  unsigned short* opwh = (unsigned short*)(w + OFF_OPW);
  unsigned short* opwl = opwh + (size_t)cD * cD;
  float* gate = w + OFF_MISC;
  int* eidx = (int*)(w + OFF_MISC + 8192);
  int* slot = (int*)(w + OFF_MISC + 16384);
  float* Psum = w + OFF_MISC + 24576;
  float* zsum = Psum + 8;
  int* counts = (int*)(Psum + 16);

  hipMemsetAsync(Psum, 0, 9 * sizeof(float), stream);

  // 1) LN1 -> split bf16
  ln_split_kernel<<<cN, 256, 0, stream>>>(src, ln1_g, ln1_b, xh, xl);
  // 1.5) weight splits
  wsplit_kernel<<<3072, 256, 0, stream>>>(in_proj_w, ipwh, ipwl, 786432);
  wsplit_kernel<<<1024, 256, 0, stream>>>(out_proj_w, opwh, opwl, 262144);
  // 2) QKV projection (split-bf16 3-term MFMA) -> qkv fp32
  gemm_bf16<true, false, false, false><<<dim3(24, 64, 1), 256, 0, stream>>>(
      xh, xl, 0, ipwh, ipwl, 0, in_proj_b, 0, nullptr, qkv, 0,
      cD, cD, cD, 3 * cD);
  // 2.5) split qkv for attention (+ V transpose)
  qkv_split_kernel<<<dim3(cS / 64, cH, cB), 256, 0, stream>>>(
      qkv, Qh, Ql, Kh, Kl, Vth, Vtl);
  // 2.6) w1 transpose+convert: [e][d][f] -> [e][f][d] bf16 (qkv region dead)
  transpose_bf16_kernel<<<dim3(64, 16, 8), 256, 0, stream>>>(w1, w1t, cD, cF);
  // 3) MFMA flash attention -> Oh/Ol split bf16
  attn_mfma_kernel<<<dim3(cS / 64, cH, cB), 256, 0, stream>>>(
      Qh, Ql, Kh, Kl, Vth, Vtl, pad, Oh, Ol);
  // 4) out_proj (split 3-term) + residual(src) -> src1 fp32
  gemm_bf16<true, false, true, false><<<dim3(8, 64, 1), 256, 0, stream>>>(
      Oh, Ol, 0, opwh, opwl, 0, out_proj_b, 0, src, src1, 0,
      cD, cD, cD, cD);
  // 5) LN2 (fp32 exact)
  ln_kernel<<<cN, 256, 0, stream>>>(src1, ln2_g, ln2_b, x2);
  // 6) router
  router_kernel<<<256, 256, 0, stream>>>(x2, router_w, router_b, pad, gate, eidx,
                                         Psum, zsum);
  // 7) capacity scan
  scan_kernel<<<1, 256, 0, stream>>>(eidx, pad, slot, counts);
  // 8) dispatch scatter -> bf16
  dispatch_bf16_kernel<<<cN, 256, 0, stream>>>(x2, slot, disp16);
  // 9) FFN1: relu(disp @ w1 + b1) -> h bf16 (plain bf16 MFMA)
  gemm_bf16<false, true, false, true><<<dim3(32, 10, 8), 256, 0, stream>>>(
      disp16, nullptr, (size_t)cCAP * cD, w1t, nullptr, (size_t)cD * cF,
      b1, cF, nullptr, hbuf16, (size_t)cCAP * cF, cD, cD, cD, cF);
  // 9.5) w2 transpose+convert: [e][f][d] -> [e][d][f] bf16 (w1t dead)
  transpose_bf16_kernel<<<dim3(16, 64, 8), 256, 0, stream>>>(w2, w2t, cF, cD);
  // 10) FFN2: h @ w2 + b2 -> obuf fp32
  gemm_bf16<false, false, false, false><<<dim3(8, 10, 8), 256, 0, stream>>>(
      hbuf16, nullptr, (size_t)cCAP * cF, w2t, nullptr, (size_t)cF * cD,
      b2, cD, nullptr, obuf, (size_t)cCAP * cD, cF, cF, cF, cD);
  // 11) gather + residual -> out
  gather_kernel<<<cN, 256, 0, stream>>>(src1, obuf, slot, gate, out);
  // 12) losses
  loss_kernel<<<1, 64, 0, stream>>>(counts, Psum, zsum, out + (size_t)cN * cD);
}

// Round 4
// 1419.285 us; speedup vs baseline: 3.9940x; 1.0485x over previous
//
#include <hip/hip_runtime.h>

// Problem constants
constexpr int cB = 4, cS = 2048, cD = 1024, cH = 16, cE = 8, cF = 4096;
constexpr int cN = cB * cS;          // 8192 tokens
constexpr int cDH = 64;
constexpr int cCAP = 1280;           // int(1.25 * 8192 / 8)

typedef __attribute__((ext_vector_type(8))) short bf16x8;
typedef __attribute__((ext_vector_type(4))) float f32x4;
typedef __attribute__((ext_vector_type(4))) unsigned short u16x4;

__device__ inline unsigned short bf16_rne(float x) {
  unsigned u = __float_as_uint(x);
  u += 0x7FFF + ((u >> 16) & 1);
  return (unsigned short)(u >> 16);
}
__device__ inline float bf16_f(unsigned short h) {
  return __uint_as_float(((unsigned)h) << 16);
}

// ---------------------------------------------------------------------------
// LayerNorm fp32 (LN2): one block per token.
// ---------------------------------------------------------------------------
__global__ __launch_bounds__(256) void ln_kernel(const float* __restrict__ x,
                                                 const float* __restrict__ g,
                                                 const float* __restrict__ bb,
                                                 float* __restrict__ y) {
  __shared__ float red[8];
  const int row = blockIdx.x;
  const int t = threadIdx.x;
  const float4 v = ((const float4*)(x + (size_t)row * cD))[t];
  float s = v.x + v.y + v.z + v.w;
#pragma unroll
  for (int m = 32; m >= 1; m >>= 1) s += __shfl_xor(s, m, 64);
  if ((t & 63) == 0) red[t >> 6] = s;
  __syncthreads();
  const float mean = (red[0] + red[1] + red[2] + red[3]) * (1.0f / cD);
  const float dx = v.x - mean, dy = v.y - mean, dz = v.z - mean, dw = v.w - mean;
  float ss = dx * dx + dy * dy + dz * dz + dw * dw;
#pragma unroll
  for (int m = 32; m >= 1; m >>= 1) ss += __shfl_xor(ss, m, 64);
  if ((t & 63) == 0) red[4 + (t >> 6)] = ss;
  __syncthreads();
  const float var = (red[4] + red[5] + red[6] + red[7]) * (1.0f / cD);
  const float inv = rsqrtf(var + 1e-5f);
  const float4 gg = ((const float4*)g)[t];
  const float4 b4 = ((const float4*)bb)[t];
  float4 o;
  o.x = dx * inv * gg.x + b4.x;
  o.y = dy * inv * gg.y + b4.y;
  o.z = dz * inv * gg.z + b4.z;
  o.w = dw * inv * gg.w + b4.w;
  ((float4*)(y + (size_t)row * cD))[t] = o;
}

// ---------------------------------------------------------------------------
// LayerNorm with split-bf16 output (LN1 -> QKV GEMM A operand).
// ---------------------------------------------------------------------------
__global__ __launch_bounds__(256) void ln_split_kernel(
    const float* __restrict__ x, const float* __restrict__ g,
    const float* __restrict__ bb, unsigned short* __restrict__ yh,
    unsigned short* __restrict__ yl) {
  __shared__ float red[8];
  const int row = blockIdx.x;
  const int t = threadIdx.x;
  const float4 v = ((const float4*)(x + (size_t)row * cD))[t];
  float s = v.x + v.y + v.z + v.w;
#pragma unroll
  for (int m = 32; m >= 1; m >>= 1) s += __shfl_xor(s, m, 64);
  if ((t & 63) == 0) red[t >> 6] = s;
  __syncthreads();
  const float mean = (red[0] + red[1] + red[2] + red[3]) * (1.0f / cD);
  const float dx = v.x - mean, dy = v.y - mean, dz = v.z - mean, dw = v.w - mean;
  float ss = dx * dx + dy * dy + dz * dz + dw * dw;
#pragma unroll
  for (int m = 32; m >= 1; m >>= 1) ss += __shfl_xor(ss, m, 64);
  if ((t & 63) == 0) red[4 + (t >> 6)] = ss;
  __syncthreads();
  const float var = (red[4] + red[5] + red[6] + red[7]) * (1.0f / cD);
  const float inv = rsqrtf(var + 1e-5f);
  const float4 gg = ((const float4*)g)[t];
  const float4 b4 = ((const float4*)bb)[t];
  const float oa[4] = {dx * inv * gg.x + b4.x, dy * inv * gg.y + b4.y,
                       dz * inv * gg.z + b4.z, dw * inv * gg.w + b4.w};
  u16x4 hh, ll;
#pragma unroll
  for (int i = 0; i < 4; i++) {
    const unsigned short h16 = bf16_rne(oa[i]);
    hh[i] = h16;
    ll[i] = bf16_rne(oa[i] - bf16_f(h16));
  }
  *(u16x4*)(yh + (size_t)row * cD + t * 4) = hh;
  *(u16x4*)(yl + (size_t)row * cD + t * 4) = ll;
}

// ---------------------------------------------------------------------------
// Weight split: fp32 -> bf16 hi/lo, same layout. n4 = element_count/4.
// ---------------------------------------------------------------------------
__global__ __launch_bounds__(256) void wsplit_kernel(const float* __restrict__ in,
                                                     unsigned short* __restrict__ hi,
                                                     unsigned short* __restrict__ lo,
                                                     int n4) {
  const int i = blockIdx.x * 256 + threadIdx.x;
  if (i >= n4) return;
  const float4 v = ((const float4*)in)[i];
  const float a[4] = {v.x, v.y, v.z, v.w};
  u16x4 hh, ll;
#pragma unroll
  for (int j = 0; j < 4; j++) {
    const unsigned short h16 = bf16_rne(a[j]);
    hh[j] = h16;
    ll[j] = bf16_rne(a[j] - bf16_f(h16));
  }
  *(u16x4*)(hi + (size_t)i * 4) = hh;
  *(u16x4*)(lo + (size_t)i * 4) = ll;
}

// ---------------------------------------------------------------------------
// Transpose + bf16 convert: in fp32 [z][R][C] -> out bf16 [z][C][R].
// ---------------------------------------------------------------------------
__global__ __launch_bounds__(256) void transpose_bf16_kernel(
    const float* __restrict__ in, unsigned short* __restrict__ outp, int Rr,
    int Cc) {
  __shared__ float T[64][65];
  const int z = blockIdx.z;
  in += (size_t)z * Rr * Cc;
  outp += (size_t)z * Rr * Cc;
  const int c0 = blockIdx.x * 64, r0 = blockIdx.y * 64;
  const int tid = threadIdx.x;
#pragma unroll
  for (int u = 0; u < 4; u++) {
    const int a = tid + u * 256;
    const int r = a >> 4, c4 = (a & 15) << 2;
    const float4 v = *(const float4*)(in + (size_t)(r0 + r) * Cc + c0 + c4);
    T[r][c4 + 0] = v.x;
    T[r][c4 + 1] = v.y;
    T[r][c4 + 2] = v.z;
    T[r][c4 + 3] = v.w;
  }
  __syncthreads();
#pragma unroll
  for (int u = 0; u < 4; u++) {
    const int a = tid + u * 256;
    const int c = a >> 4, r4 = (a & 15) << 2;
    u16x4 o;
#pragma unroll
    for (int i = 0; i < 4; i++) o[i] = bf16_rne(T[r4 + i][c]);
    *(u16x4*)(outp + (size_t)(c0 + c) * Rr + r0 + r4) = o;
  }
}

// ---------------------------------------------------------------------------
// bf16 MFMA GEMM: C[M,N] = A[M,K] * B[N,K]^T + bias.
// OUT: 0 = fp32 C (+RELU/+RESID), 1 = bf16 C, 2 = fused QKV-split epilogue
// (writes Qh/Ql/Kh/Kl [b,h,s,d] and Vth/Vtl [b,h,d,s] split-bf16 directly).
// 128x128 tile, BK=32, 4 waves x (4x4 of 16x16x32 MFMA), LDS stride 40 u16.
// ---------------------------------------------------------------------------
template <bool SPLIT, bool RELU, bool RESID, int OUT>
__global__ __launch_bounds__(256) void gemm_bf16(
    const unsigned short* __restrict__ Ah, const unsigned short* __restrict__ Al,
    size_t sA,
    const unsigned short* __restrict__ Bh, const unsigned short* __restrict__ Bl,
    size_t sB,
    const float* __restrict__ bias, size_t sBias,
    const float* __restrict__ R,
    void* __restrict__ Cv, size_t sC,
    int K, int lda, int ldb, int ldc,
    unsigned short* __restrict__ Qh, unsigned short* __restrict__ Ql,
    unsigned short* __restrict__ Kh, unsigned short* __restrict__ Kl,
    unsigned short* __restrict__ Vth, unsigned short* __restrict__ Vtl) {
  __shared__ unsigned short AsH[128 * 40];
  __shared__ unsigned short BsH[128 * 40];
  __shared__ unsigned short AsL[SPLIT ? 128 * 40 : 8];
  __shared__ unsigned short BsL[SPLIT ? 128 * 40 : 8];
  const int z = blockIdx.z;
  Ah += (size_t)z * sA;
  Bh += (size_t)z * sB;
  if constexpr (SPLIT) {
    Al += (size_t)z * sA;
    Bl += (size_t)z * sB;
  }
  bias += (size_t)z * sBias;
  const int n0 = blockIdx.x * 128, m0 = blockIdx.y * 128;
  const int tid = threadIdx.x;
  const int wid = tid >> 6, lane = tid & 63;
  const int ln = lane & 15, quad = lane >> 4;
  const int wm = (wid >> 1) * 64, wn = (wid & 1) * 64;

  f32x4 acc[4][4];
#pragma unroll
  for (int i = 0; i < 4; i++)
#pragma unroll
    for (int j = 0; j < 4; j++) acc[i][j] = (f32x4){0.f, 0.f, 0.f, 0.f};

  for (int k0 = 0; k0 < K; k0 += 32) {
    __syncthreads();
#pragma unroll
    for (int u = 0; u < 2; u++) {
      const int c = tid + u * 256;           // 0..511
      const int row = c >> 2, ko = (c & 3) << 3;
      const int ld = row * 40 + ko;
      *(uint4*)&AsH[ld] = *(const uint4*)(Ah + (size_t)(m0 + row) * lda + k0 + ko);
      *(uint4*)&BsH[ld] = *(const uint4*)(Bh + (size_t)(n0 + row) * ldb + k0 + ko);
      if constexpr (SPLIT) {
        *(uint4*)&AsL[ld] = *(const uint4*)(Al + (size_t)(m0 + row) * lda + k0 + ko);
        *(uint4*)&BsL[ld] = *(const uint4*)(Bl + (size_t)(n0 + row) * ldb + k0 + ko);
      }
    }
    __syncthreads();
    bf16x8 bh[4], bl[4];
#pragma unroll
    for (int nt = 0; nt < 4; nt++) {
      bh[nt] = *(const bf16x8*)&BsH[(wn + nt * 16 + ln) * 40 + quad * 8];
      if constexpr (SPLIT)
        bl[nt] = *(const bf16x8*)&BsL[(wn + nt * 16 + ln) * 40 + quad * 8];
    }
#pragma unroll
    for (int mt = 0; mt < 4; mt++) {
      const bf16x8 ah = *(const bf16x8*)&AsH[(wm + mt * 16 + ln) * 40 + quad * 8];
      bf16x8 al;
      if constexpr (SPLIT)
        al = *(const bf16x8*)&AsL[(wm + mt * 16 + ln) * 40 + quad * 8];
#pragma unroll
      for (int nt = 0; nt < 4; nt++) {
        acc[mt][nt] =
            __builtin_amdgcn_mfma_f32_16x16x32_bf16(ah, bh[nt], acc[mt][nt], 0, 0, 0);
        if constexpr (SPLIT) {
          acc[mt][nt] =
              __builtin_amdgcn_mfma_f32_16x16x32_bf16(al, bh[nt], acc[mt][nt], 0, 0, 0);
          acc[mt][nt] =
              __builtin_amdgcn_mfma_f32_16x16x32_bf16(ah, bl[nt], acc[mt][nt], 0, 0, 0);
        }
      }
    }
  }
  // ---- epilogue ----
  if constexpr (OUT == 2) {
    // fused QKV split: col -> (sec,h,d); row -> (b,s). sec/h wave-uniform.
#pragma unroll
    for (int mt = 0; mt < 4; mt++) {
      const int row0 = m0 + wm + mt * 16 + quad * 4;
      const int b_ = row0 >> 11, s0_ = row0 & 2047;
      const size_t bbase = (size_t)b_ * cH * cS * cDH;
#pragma unroll
      for (int nt = 0; nt < 4; nt++) {
        const int col = n0 + wn + nt * 16 + ln;
        const float bv = bias[col];
        const int sec = col >> 10;
        const int f = col & 1023;
        const int hh = f >> 6, d = f & 63;
        const size_t bh_off = bbase + (size_t)hh * cS * cDH;
        float vals[4];
#pragma unroll
        for (int r = 0; r < 4; r++) vals[r] = acc[mt][nt][r] + bv;
        if (sec == 2) {
          u16x4 hi4, lo4;
#pragma unroll
          for (int r = 0; r < 4; r++) {
            const unsigned short h16 = bf16_rne(vals[r]);
            hi4[r] = h16;
            lo4[r] = bf16_rne(vals[r] - bf16_f(h16));
          }
          const size_t idx = bh_off + (size_t)d * cS + s0_;
          *(u16x4*)(Vth + idx) = hi4;
          *(u16x4*)(Vtl + idx) = lo4;
        } else {
          unsigned short* dsth = (sec == 0) ? Qh : Kh;
          unsigned short* dstl = (sec == 0) ? Ql : Kl;
#pragma unroll
          for (int r = 0; r < 4; r++) {
            const unsigned short h16 = bf16_rne(vals[r]);
            const size_t idx = bh_off + (size_t)(s0_ + r) * cDH + d;
            dsth[idx] = h16;
            dstl[idx] = bf16_rne(vals[r] - bf16_f(h16));
          }
        }
      }
    }
  } else {
    float* Cf = nullptr;
    unsigned short* Cb = nullptr;
    if constexpr (OUT == 1)
      Cb = (unsigned short*)Cv + (size_t)z * sC;
    else
      Cf = (float*)Cv + (size_t)z * sC;
#pragma unroll
    for (int mt = 0; mt < 4; mt++) {
#pragma unroll
      for (int nt = 0; nt < 4; nt++) {
        const int col = n0 + wn + nt * 16 + ln;
        const float bv = bias[col];
#pragma unroll
        for (int r = 0; r < 4; r++) {
          const int row = m0 + wm + mt * 16 + quad * 4 + r;
          float v = acc[mt][nt][r] + bv;
          if constexpr (RELU) v = fmaxf(v, 0.f);
          if constexpr (RESID) v += R[(size_t)row * ldc + col];
          if constexpr (OUT == 1)
            Cb[(size_t)row * ldc + col] = bf16_rne(v);
          else
            Cf[(size_t)row * ldc + col] = v;
        }
      }
    }
  }
}

// ---------------------------------------------------------------------------
// Flash attention, split-bf16 MFMA, TRANSPOSED dataflow:
//   S^T = K·Q^T  (D rows = key, cols = q=ln) — each lane owns ONE query.
//   softmax: 16 in-register keys + xor(16,32) cross-quad reduce (4 shuffles).
//   P written as u16x4 ds_write_b64 (2-way banks, free).
//   O^T = V^T·P^T (A=V frag, B=P frag) — O cols = q=ln, alpha is lane-local.
// ---------------------------------------------------------------------------
__global__ __launch_bounds__(256) void attn_mfma_kernel(
    const unsigned short* __restrict__ Qh, const unsigned short* __restrict__ Ql,
    const unsigned short* __restrict__ Kh, const unsigned short* __restrict__ Kl,
    const unsigned short* __restrict__ Vth, const unsigned short* __restrict__ Vtl,
    const unsigned char* __restrict__ pad, unsigned short* __restrict__ Oh,
    unsigned short* __restrict__ Ol) {
  __shared__ unsigned short KsH[64 * 72];
  __shared__ unsigned short KsL[64 * 72];
  __shared__ unsigned short VsH[64 * 72];
  __shared__ unsigned short VsL[64 * 72];
  __shared__ unsigned short PsH[4 * 16 * 72];
  __shared__ unsigned short PsL[4 * 16 * 72];
  __shared__ float Mk[64];

  const int q0 = blockIdx.x << 6;
  const int h = blockIdx.y, b = blockIdx.z;
  const int tid = threadIdx.x;
  const int wid = tid >> 6, lane = tid & 63;
  const int ln = lane & 15, quad = lane >> 4;
  constexpr float SC2 = 0.125f * 1.4426950408889634f;  // 1/sqrt(64) * log2(e)

  const size_t bh = (size_t)(b * cH + h);
  const unsigned short* gKh = Kh + bh * cS * cDH;
  const unsigned short* gKl = Kl + bh * cS * cDH;
  const unsigned short* gVh = Vth + bh * cDH * cS;
  const unsigned short* gVl = Vtl + bh * cDH * cS;

  // Q fragment (B-operand): lane q = ln, k = quad*8+j
  const size_t qbase = (bh * cS + q0 + wid * 16 + ln) * cDH;
  bf16x8 qh[2], ql[2];
#pragma unroll
  for (int ks = 0; ks < 2; ks++) {
    qh[ks] = *(const bf16x8*)(Qh + qbase + ks * 32 + quad * 8);
    ql[ks] = *(const bf16x8*)(Ql + qbase + ks * 32 + quad * 8);
  }

  f32x4 Oc[4];  // O^T: rows d (dt*16+quad*4+r), col q=ln
#pragma unroll
  for (int dt = 0; dt < 4; dt++) Oc[dt] = (f32x4){0.f, 0.f, 0.f, 0.f};
  float mprev = -1e30f, lrun = 0.f;  // per-lane (its q)

  for (int kt = 0; kt < cS / 64; kt++) {
    const int k0 = kt << 6;
    __syncthreads();
#pragma unroll
    for (int u = 0; u < 2; u++) {
      const int a = tid + (u << 8);
      const int row = a >> 3, c8 = (a & 7) << 3;
      const int ld = row * 72 + c8;
      *(uint4*)&KsH[ld] = *(const uint4*)(gKh + (size_t)(k0 + row) * cDH + c8);
      *(uint4*)&KsL[ld] = *(const uint4*)(gKl + (size_t)(k0 + row) * cDH + c8);
      *(uint4*)&VsH[ld] = *(const uint4*)(gVh + (size_t)row * cS + k0 + c8);
      *(uint4*)&VsL[ld] = *(const uint4*)(gVl + (size_t)row * cS + k0 + c8);
    }
    if (tid < 64) Mk[tid] = pad[b * cS + k0 + tid] ? -1e30f : 0.0f;
    __syncthreads();

    // ---- S^T = K Q^T (split 3-term). Lane: keys st*16+quad*4+r, q=ln ----
    float sf[4][4];
#pragma unroll
    for (int st = 0; st < 4; st++) {
      f32x4 acc = (f32x4){0.f, 0.f, 0.f, 0.f};
      const unsigned short* krH = &KsH[(st * 16 + ln) * 72];
      const unsigned short* krL = &KsL[(st * 16 + ln) * 72];
#pragma unroll
      for (int ks = 0; ks < 2; ks++) {
        const bf16x8 kh = *(const bf16x8*)(krH + ks * 32 + quad * 8);
        const bf16x8 kl = *(const bf16x8*)(krL + ks * 32 + quad * 8);
        acc = __builtin_amdgcn_mfma_f32_16x16x32_bf16(kh, qh[ks], acc, 0, 0, 0);
        acc = __builtin_amdgcn_mfma_f32_16x16x32_bf16(kl, qh[ks], acc, 0, 0, 0);
        acc = __builtin_amdgcn_mfma_f32_16x16x32_bf16(kh, ql[ks], acc, 0, 0, 0);
      }
      const float4 mkv = *(const float4*)&Mk[st * 16 + quad * 4];
      sf[st][0] = acc[0] * SC2 + mkv.x;
      sf[st][1] = acc[1] * SC2 + mkv.y;
      sf[st][2] = acc[2] * SC2 + mkv.z;
      sf[st][3] = acc[3] * SC2 + mkv.w;
    }
    // ---- online softmax: one q per lane ----
    float vm = -1e30f;
#pragma unroll
    for (int st = 0; st < 4; st++)
#pragma unroll
      for (int r = 0; r < 4; r++) vm = fmaxf(vm, sf[st][r]);
    vm = fmaxf(vm, __shfl_xor(vm, 16, 64));
    vm = fmaxf(vm, __shfl_xor(vm, 32, 64));
    const float mnew = fmaxf(mprev, vm);
    const float alpha = exp2f(mprev - mnew);
    float rs = 0.f;
    u16x4 phv[4], plv[4];
#pragma unroll
    for (int st = 0; st < 4; st++) {
#pragma unroll
      for (int r = 0; r < 4; r++) {
        const float p = exp2f(sf[st][r] - mnew);
        rs += p;
        const unsigned short h16 = bf16_rne(p);
        phv[st][r] = h16;
        plv[st][r] = bf16_rne(p - bf16_f(h16));
      }
    }
    rs += __shfl_xor(rs, 16, 64);
    rs += __shfl_xor(rs, 32, 64);
    lrun = lrun * alpha + rs;
    mprev = mnew;
#pragma unroll
    for (int dt = 0; dt < 4; dt++) {
      Oc[dt][0] *= alpha;
      Oc[dt][1] *= alpha;
      Oc[dt][2] *= alpha;
      Oc[dt][3] *= alpha;
    }
    // P -> LDS, A/B-frag layout [q=ln row][key col], u16x4 stores (b64)
    const int pbase = wid * 1152 + ln * 72 + quad * 4;
#pragma unroll
    for (int st = 0; st < 4; st++) {
      *(u16x4*)&PsH[pbase + st * 16] = phv[st];
      *(u16x4*)&PsL[pbase + st * 16] = plv[st];
    }
    // ---- O^T += V^T P^T (split 3-term) ----
    const unsigned short* pwH = PsH + wid * 1152 + ln * 72;
    const unsigned short* pwL = PsL + wid * 1152 + ln * 72;
#pragma unroll
    for (int dt = 0; dt < 4; dt++) {
      f32x4 acc = Oc[dt];
      const unsigned short* vrH = &VsH[(dt * 16 + ln) * 72];
      const unsigned short* vrL = &VsL[(dt * 16 + ln) * 72];
#pragma unroll
      for (int ks = 0; ks < 2; ks++) {
        const bf16x8 vh = *(const bf16x8*)(vrH + ks * 32 + quad * 8);
        const bf16x8 vl = *(const bf16x8*)(vrL + ks * 32 + quad * 8);
        const bf16x8 pbh = *(const bf16x8*)(pwH + ks * 32 + quad * 8);
        const bf16x8 pbl = *(const bf16x8*)(pwL + ks * 32 + quad * 8);
        acc = __builtin_amdgcn_mfma_f32_16x16x32_bf16(vh, pbh, acc, 0, 0, 0);
        acc = __builtin_amdgcn_mfma_f32_16x16x32_bf16(vh, pbl, acc, 0, 0, 0);
        acc = __builtin_amdgcn_mfma_f32_16x16x32_bf16(vl, pbh, acc, 0, 0, 0);
      }
      Oc[dt] = acc;
    }
  }
  // ---- epilogue: normalize, split-bf16 store (u16x4 per dt) ----
  const float inv = 1.0f / lrun;
  const int tok = b * cS + q0 + wid * 16 + ln;
#pragma unroll
  for (int dt = 0; dt < 4; dt++) {
    u16x4 oh4, ol4;
#pragma unroll
    for (int r = 0; r < 4; r++) {
      const float v = Oc[dt][r] * inv;
      const unsigned short h16 = bf16_rne(v);
      oh4[r] = h16;
      ol4[r] = bf16_rne(v - bf16_f(h16));
    }
    const size_t idx = (size_t)tok * cD + h * cDH + dt * 16 + quad * 4;
    *(u16x4*)(Oh + idx) = oh4;
    *(u16x4*)(Ol + idx) = ol4;
  }
}

// ---------------------------------------------------------------------------
// Router (fp32 exact — feeds the discontinuous argmax).
// ---------------------------------------------------------------------------
__global__ __launch_bounds__(256) void router_kernel(
    const float* __restrict__ x2, const float* __restrict__ rw,
    const float* __restrict__ rb, const unsigned char* __restrict__ pad,
    float* __restrict__ gate, int* __restrict__ eidx, float* __restrict__ Psum,
    float* __restrict__ zsum) {
  __shared__ float Pacc[8];
  __shared__ float Zacc;
  if (threadIdx.x < 8) Pacc[threadIdx.x] = 0.f;
  if (threadIdx.x == 8) Zacc = 0.f;
  __syncthreads();
  const int tid = threadIdx.x, wid = tid >> 6, lane = tid & 63;
  const int e = lane & 7, dbase = lane >> 3;
  for (int tok = blockIdx.x * 4 + wid; tok < cN; tok += gridDim.x * 4) {
    const float* xr = x2 + (size_t)tok * cD;
    float partial = 0.f;
#pragma unroll 8
    for (int i = 0; i < cD / 8; i++) {
      const int d = dbase + i * 8;
      partial += xr[d] * rw[d * 8 + e];
    }
    partial += __shfl_xor(partial, 8, 64);
    partial += __shfl_xor(partial, 16, 64);
    partial += __shfl_xor(partial, 32, 64);
    const float logit = partial + rb[e];
    float mx = logit;
    mx = fmaxf(mx, __shfl_xor(mx, 1, 64));
    mx = fmaxf(mx, __shfl_xor(mx, 2, 64));
    mx = fmaxf(mx, __shfl_xor(mx, 4, 64));
    const float ex = __expf(logit - mx);
    float sm = ex;
    sm += __shfl_xor(sm, 1, 64);
    sm += __shfl_xor(sm, 2, 64);
    sm += __shfl_xor(sm, 4, 64);
    const float prob = ex / sm;
    float bv = logit;
    int bi = e;
#pragma unroll
    for (int m = 1; m < 8; m <<= 1) {
      const float ov = __shfl_xor(bv, m, 64);
      const int oi = __shfl_xor(bi, m, 64);
      if (ov > bv || (ov == bv && oi < bi)) {
        bv = ov;
        bi = oi;
      }
    }
    const float g = __shfl(prob, (lane & 0x38) | bi, 64);
    const bool valid = (pad[tok] == 0);
    if (lane == 0) {
      eidx[tok] = bi;
      gate[tok] = g;
    }
    if (valid) {
      if (lane < 8) atomicAdd(&Pacc[lane], prob);
      if (lane == 0) {
        const float lse = mx + logf(sm);
        atomicAdd(&Zacc, lse * lse);
      }
    }
  }
  __syncthreads();
  if (threadIdx.x < 8) atomicAdd(&Psum[threadIdx.x], Pacc[threadIdx.x]);
  if (threadIdx.x == 8) atomicAdd(zsum, Zacc);
}

// ---------------------------------------------------------------------------
// Capacity scan (unchanged).
// ---------------------------------------------------------------------------
__global__ __launch_bounds__(256) void scan_kernel(const int* __restrict__ eidx,
                                                   const unsigned char* __restrict__ pad,
                                                   int* __restrict__ slot,
                                                   int* __restrict__ counts) {
  __shared__ int cnt[256][8];
  const int t = threadIdx.x;
  int lc[8] = {0, 0, 0, 0, 0, 0, 0, 0};
  const int base = t * 32;
  for (int i = 0; i < 32; i++) {
    const int tok = base + i;
    if (!pad[tok]) lc[eidx[tok]]++;
  }
#pragma unroll
  for (int e2 = 0; e2 < 8; e2++) cnt[t][e2] = lc[e2];
  __syncthreads();
  if (t < 8) {
    int run = 0;
    for (int i = 0; i < 256; i++) {
      const int v = cnt[i][t];
      cnt[i][t] = run;
      run += v;
    }
    counts[t] = run;
  }
  __syncthreads();
  int off[8];
#pragma unroll
  for (int e2 = 0; e2 < 8; e2++) off[e2] = cnt[t][e2];
  for (int i = 0; i < 32; i++) {
    const int tok = base + i;
    if (!pad[tok]) {
      const int e2 = eidx[tok];
      const int p = off[e2]++;
      slot[tok] = (p < cCAP) ? (e2 * cCAP + p) : -1;
    } else {
      slot[tok] = -1;
    }
  }
}

__global__ __launch_bounds__(256) void dispatch_bf16_kernel(
    const float* __restrict__ x2, const int* __restrict__ slot,
    unsigned short* __restrict__ disp) {
  const int tok = blockIdx.x;
  const int s = slot[tok];
  if (s < 0) return;
  const float4 v = ((const float4*)(x2 + (size_t)tok * cD))[threadIdx.x];
  u16x4 o;
  o[0] = bf16_rne(v.x);
  o[1] = bf16_rne(v.y);
  o[2] = bf16_rne(v.z);
  o[3] = bf16_rne(v.w);
  *(u16x4*)(disp + (size_t)s * cD + threadIdx.x * 4) = o;
}

__global__ __launch_bounds__(256) void gather_kernel(const float* __restrict__ src1,
                                                     const float* __restrict__ o,
                                                     const int* __restrict__ slot,
                                                     const float* __restrict__ gate,
                                                     float* __restrict__ out) {
  const int tok = blockIdx.x;
  float4 r = ((const float4*)(src1 + (size_t)tok * cD))[threadIdx.x];
  const int s = slot[tok];
  if (s >= 0) {
    const float g = gate[tok];
    const float4 ov = ((const float4*)(o + (size_t)s * cD))[threadIdx.x];
    r.x += g * ov.x;
    r.y += g * ov.y;
    r.z += g * ov.z;
    r.w += g * ov.w;
  }
  ((float4*)(out + (size_t)tok * cD))[threadIdx.x] = r;
}

__global__ void loss_kernel(const int* __restrict__ counts,
                            const float* __restrict__ Psum,
                            const float* __restrict__ zsum,
                            float* __restrict__ out) {
  if (threadIdx.x == 0) {
    int tot = 0;
    for (int e2 = 0; e2 < 8; e2++) tot += counts[e2];
    const float denom = fmaxf((float)tot, 1.0f);
    float lp = 0.f;
    for (int e2 = 0; e2 < 8; e2++)
      lp += ((float)counts[e2] / denom) * (Psum[e2] / denom);
    out[0] = 8.0f * lp;
    out[1] = zsum[0] / denom;
  }
}

// ---------------------------------------------------------------------------
// Workspace layout (float units), sequential lifetimes:
// R_A: w1t bf16 (->FFN1) / w2t bf16 (->FFN2)   (qkv fp32 no longer exists)
// R_B: Q..Vt splits (QKV gemm->attn) / h bf16 (FFN1->FFN2)
// R_XHL: xh+xl (LN1->QKV) / Oh+Ol (attn->out_proj) / disp bf16 (->FFN1)
// R_X2O: x2 (LN2->dispatch) / obuf fp32 (FFN2->gather)
// ---------------------------------------------------------------------------
constexpr size_t OFF_A = 0;              // 25,165,824 floats
constexpr size_t OFF_B = 25165824;       // 25,165,824
constexpr size_t OFF_XHL = 50331648;     // 8,388,608
constexpr size_t OFF_SRC1 = 58720256;    // 8,388,608
constexpr size_t OFF_X2O = 67108864;     // 10,485,760
constexpr size_t OFF_IPW = 77594624;     // 3,145,728
constexpr size_t OFF_OPW = 80740352;     // 1,048,576
constexpr size_t OFF_MISC = 81788928;

extern "C" void kernel_launch(void* const* d_in, const int* in_sizes, int n_in,
                              void* d_out, int out_size, void* d_ws, size_t ws_size,
                              hipStream_t stream) {
  (void)in_sizes; (void)n_in; (void)out_size; (void)ws_size;
  const float* src = (const float*)d_in[0];
  const unsigned char* pad = (const unsigned char*)d_in[1];
  const float* ln1_g = (const float*)d_in[2];
  const float* ln1_b = (const float*)d_in[3];
  const float* in_proj_w = (const float*)d_in[4];
  const float* in_proj_b = (const float*)d_in[5];
  const float* out_proj_w = (const float*)d_in[6];
  const float* out_proj_b = (const float*)d_in[7];
  const float* ln2_g = (const float*)d_in[8];
  const float* ln2_b = (const float*)d_in[9];
  const float* router_w = (const float*)d_in[10];
  const float* router_b = (const float*)d_in[11];
  const float* w1 = (const float*)d_in[12];
  const float* b1 = (const float*)d_in[13];
  const float* w2 = (const float*)d_in[14];
  const float* b2 = (const float*)d_in[15];
  float* out = (float*)d_out;
  float* w = (float*)d_ws;

  unsigned short* w1t = (unsigned short*)(w + OFF_A);
  unsigned short* w2t = (unsigned short*)(w + OFF_A);   // after w1t dead
  unsigned short* usB = (unsigned short*)(w + OFF_B);
  constexpr size_t SPN = (size_t)cN * cD;               // 8,388,608 u16
  unsigned short* Qh = usB + 0 * SPN;
  unsigned short* Ql = usB + 1 * SPN;
  unsigned short* Kh = usB + 2 * SPN;
  unsigned short* Kl = usB + 3 * SPN;
  unsigned short* Vth = usB + 4 * SPN;
  unsigned short* Vtl = usB + 5 * SPN;
  unsigned short* hbuf16 = usB;                          // after splits dead
  unsigned short* xh = (unsigned short*)(w + OFF_XHL);
  unsigned short* xl = xh + SPN;
  unsigned short* Oh = xh;                               // after xh/xl dead
  unsigned short* Ol = xh + SPN;
  unsigned short* disp16 = xh;                           // after Oh/Ol dead
  float* src1 = w + OFF_SRC1;
  float* x2 = w + OFF_X2O;
  float* obuf = w + OFF_X2O;                             // after x2 dead
  unsigned short* ipwh = (unsigned short*)(w + OFF_IPW);
  unsigned short* ipwl = ipwh + (size_t)3 * cD * cD;
  unsigned short* opwh = (unsigned short*)(w + OFF_OPW);
  unsigned short* opwl = opwh + (size_t)cD * cD;
  float* gate = w + OFF_MISC;
  int* eidx = (int*)(w + OFF_MISC + 8192);
  int* slot = (int*)(w + OFF_MISC + 16384);
  float* Psum = w + OFF_MISC + 24576;
  float* zsum = Psum + 8;
  int* counts = (int*)(Psum + 16);

  hipMemsetAsync(Psum, 0, 9 * sizeof(float), stream);

  // 1) LN1 -> split bf16
  ln_split_kernel<<<cN, 256, 0, stream>>>(src, ln1_g, ln1_b, xh, xl);
  // 1.5) weight splits
  wsplit_kernel<<<3072, 256, 0, stream>>>(in_proj_w, ipwh, ipwl, 786432);
  wsplit_kernel<<<1024, 256, 0, stream>>>(out_proj_w, opwh, opwl, 262144);
  // 2) QKV projection (split 3-term) with FUSED qkv-split epilogue
  gemm_bf16<true, false, false, 2><<<dim3(24, 64, 1), 256, 0, stream>>>(
      xh, xl, 0, ipwh, ipwl, 0, in_proj_b, 0, nullptr, nullptr, 0,
      cD, cD, cD, 0, Qh, Ql, Kh, Kl, Vth, Vtl);
  // 2.5) w1 transpose+convert: [e][d][f] -> [e][f][d] bf16
  transpose_bf16_kernel<<<dim3(64, 16, 8), 256, 0, stream>>>(w1, w1t, cD, cF);
  // 3) MFMA flash attention (transposed dataflow) -> Oh/Ol split bf16
  attn_mfma_kernel<<<dim3(cS / 64, cH, cB), 256, 0, stream>>>(
      Qh, Ql, Kh, Kl, Vth, Vtl, pad, Oh, Ol);
  // 4) out_proj (split 3-term) + residual(src) -> src1 fp32
  gemm_bf16<true, false, true, 0><<<dim3(8, 64, 1), 256, 0, stream>>>(
      Oh, Ol, 0, opwh, opwl, 0, out_proj_b, 0, src, src1, 0,
      cD, cD, cD, cD, nullptr, nullptr, nullptr, nullptr, nullptr, nullptr);
  // 5) LN2 (fp32 exact)
  ln_kernel<<<cN, 256, 0, stream>>>(src1, ln2_g, ln2_b, x2);
  // 6) router
  router_kernel<<<256, 256, 0, stream>>>(x2, router_w, router_b, pad, gate, eidx,
                                         Psum, zsum);
  // 7) capacity scan
  scan_kernel<<<1, 256, 0, stream>>>(eidx, pad, slot, counts);
  // 8) dispatch scatter -> bf16
  dispatch_bf16_kernel<<<cN, 256, 0, stream>>>(x2, slot, disp16);
  // 9) FFN1: relu(disp @ w1 + b1) -> h bf16 (plain bf16 MFMA)
  gemm_bf16<false, true, false, 1><<<dim3(32, 10, 8), 256, 0, stream>>>(
      disp16, nullptr, (size_t)cCAP * cD, w1t, nullptr, (size_t)cD * cF,
      b1, cF, nullptr, hbuf16, (size_t)cCAP * cF, cD, cD, cD, cF,
      nullptr, nullptr, nullptr, nullptr, nullptr, nullptr);
  // 9.5) w2 transpose+convert: [e][f][d] -> [e][d][f] bf16 (w1t dead)
  transpose_bf16_kernel<<<dim3(16, 64, 8), 256, 0, stream>>>(w2, w2t, cF, cD);
  // 10) FFN2: h @ w2 + b2 -> obuf fp32
  gemm_bf16<false, false, false, 0><<<dim3(8, 10, 8), 256, 0, stream>>>(
      hbuf16, nullptr, (size_t)cCAP * cF, w2t, nullptr, (size_t)cF * cD,
      b2, cD, nullptr, obuf, (size_t)cCAP * cD, cF, cF, cF, cD,
      nullptr, nullptr, nullptr, nullptr, nullptr, nullptr);
  // 11) gather + residual -> out
  gather_kernel<<<cN, 256, 0, stream>>>(src1, obuf, slot, gate, out);
  // 12) losses
  loss_kernel<<<1, 64, 0, stream>>>(counts, Psum, zsum, out + (size_t)cN * cD);
}